// Round 1
// baseline (736.657 us; speedup 1.0000x reference)
//
#include <hip/hip_runtime.h>
#include <hip/hip_bf16.h>
#include <math.h>
#include <stdint.h>

#define DIMC   512
#define NHEAD  8
#define HD     64
#define NTOK   1024
#define MTOK   256
#define BSZ    8
#define LN_EPS 1e-5f

// ---------------------------------------------------------------------------
// Mask dtype probe: bool may arrive as int32 (0/1 words), uint8, or float32.
// flag: 0 = int32, 1 = uint8, 2 = float32
// ---------------------------------------------------------------------------
__global__ void detect_mask_kernel(const unsigned int* __restrict__ m,
                                   int* __restrict__ flag)
{
    if (blockIdx.x == 0 && threadIdx.x == 0) {
        int all01 = 1, allf = 1;
        for (int i = 0; i < 64; ++i) {
            unsigned int w = m[i];
            if (w > 1u) all01 = 0;
            if (w != 0u && w != 0x3F800000u) allf = 0;
        }
        *flag = all01 ? 0 : (allf ? 2 : 1);
    }
}

// ---------------------------------------------------------------------------
// Generic fp32 GEMM: C(M,N) = A(M,K) @ B(N,K)^T (+bias). torch Linear layout.
// 256 threads, TM x TN micro-tile per thread.
// ---------------------------------------------------------------------------
template<int BM, int BN, int BK, int TM, int TN>
__global__ __launch_bounds__(256)
void gemm_nt(const float* __restrict__ A, const float* __restrict__ B,
             const float* __restrict__ bias, float* __restrict__ C,
             int M, int N, int K)
{
    __shared__ __align__(16) float As[BK][BM + 4];
    __shared__ __align__(16) float Bs[BK][BN + 4];
    constexpr int AV = (BM * BK) / (4 * 256);
    constexpr int BV = (BN * BK) / (4 * 256);

    const int tid = threadIdx.x;
    const int tx = tid & 15;
    const int ty = tid >> 4;
    const size_t bm = (size_t)blockIdx.y * BM;
    const size_t bn = (size_t)blockIdx.x * BN;

    float acc[TM][TN];
#pragma unroll
    for (int i = 0; i < TM; ++i)
#pragma unroll
        for (int j = 0; j < TN; ++j) acc[i][j] = 0.f;

    for (int kt = 0; kt < K; kt += BK) {
        float4 ast[AV], bst[BV];
#pragma unroll
        for (int t = 0; t < AV; ++t) {
            const int idx = tid + t * 256;
            const int r = idx >> 2, cc = (idx & 3) * 4;
            ast[t] = *(const float4*)(A + (bm + r) * K + kt + cc);
        }
#pragma unroll
        for (int t = 0; t < BV; ++t) {
            const int idx = tid + t * 256;
            const int r = idx >> 2, cc = (idx & 3) * 4;
            bst[t] = *(const float4*)(B + (bn + r) * K + kt + cc);
        }
        __syncthreads();   // previous iteration's LDS reads done
#pragma unroll
        for (int t = 0; t < AV; ++t) {
            const int idx = tid + t * 256;
            const int r = idx >> 2, cc = (idx & 3) * 4;
            As[cc + 0][r] = ast[t].x; As[cc + 1][r] = ast[t].y;
            As[cc + 2][r] = ast[t].z; As[cc + 3][r] = ast[t].w;
        }
#pragma unroll
        for (int t = 0; t < BV; ++t) {
            const int idx = tid + t * 256;
            const int r = idx >> 2, cc = (idx & 3) * 4;
            Bs[cc + 0][r] = bst[t].x; Bs[cc + 1][r] = bst[t].y;
            Bs[cc + 2][r] = bst[t].z; Bs[cc + 3][r] = bst[t].w;
        }
        __syncthreads();   // LDS writes visible
#pragma unroll
        for (int kk = 0; kk < BK; ++kk) {
            float a[TM], bb[TN];
#pragma unroll
            for (int i4 = 0; i4 < TM; i4 += 4) {
                const float4 t4 = *(const float4*)(&As[kk][ty * TM + i4]);
                a[i4 + 0] = t4.x; a[i4 + 1] = t4.y; a[i4 + 2] = t4.z; a[i4 + 3] = t4.w;
            }
#pragma unroll
            for (int j4 = 0; j4 < TN; j4 += 4) {
                const float4 t4 = *(const float4*)(&Bs[kk][tx * TN + j4]);
                bb[j4 + 0] = t4.x; bb[j4 + 1] = t4.y; bb[j4 + 2] = t4.z; bb[j4 + 3] = t4.w;
            }
#pragma unroll
            for (int i = 0; i < TM; ++i)
#pragma unroll
                for (int j = 0; j < TN; ++j)
                    acc[i][j] += a[i] * bb[j];
        }
    }

    const size_t col0 = bn + tx * TN;
#pragma unroll
    for (int i = 0; i < TM; ++i) {
        const size_t row = bm + ty * TM + i;
#pragma unroll
        for (int j4 = 0; j4 < TN; j4 += 4) {
            float4 v;
            v.x = acc[i][j4 + 0]; v.y = acc[i][j4 + 1];
            v.z = acc[i][j4 + 2]; v.w = acc[i][j4 + 3];
            if (bias != nullptr) {
                v.x += bias[col0 + j4 + 0]; v.y += bias[col0 + j4 + 1];
                v.z += bias[col0 + j4 + 2]; v.w += bias[col0 + j4 + 3];
            }
            *(float4*)(C + row * N + col0 + j4) = v;
        }
    }
}

// ---------------------------------------------------------------------------
// Fused depthwise 2x2/stride-2 conv + bias + LayerNorm over C.
// One block per output token (b, n'), 512 threads = one channel each.
// ---------------------------------------------------------------------------
__global__ __launch_bounds__(512)
void conv_ln_kernel(const float* __restrict__ x, const float* __restrict__ srw,
                    const float* __restrict__ srb, const float* __restrict__ lng,
                    const float* __restrict__ lnb, float* __restrict__ xr)
{
    const int c  = threadIdx.x;        // 0..511
    const int bn = blockIdx.x;         // B*256
    const int b  = bn >> 8;
    const int np = bn & 255;
    const int ho = np >> 4, wo = np & 15;
    const int n00 = (ho * 2) * 32 + wo * 2;

    const float* xb = x + ((size_t)b * NTOK) * DIMC + c;
    const float4 w = *(const float4*)(srw + c * 4);
    float y = srb[c]
            + xb[(size_t)(n00     ) * DIMC] * w.x
            + xb[(size_t)(n00 + 1 ) * DIMC] * w.y
            + xb[(size_t)(n00 + 32) * DIMC] * w.z
            + xb[(size_t)(n00 + 33) * DIMC] * w.w;

    float s = y, s2 = y * y;
#pragma unroll
    for (int off = 32; off > 0; off >>= 1) {
        s  += __shfl_down(s,  off);
        s2 += __shfl_down(s2, off);
    }
    __shared__ float red[16];
    __shared__ float stats[2];
    const int lane = c & 63, wid = c >> 6;
    if (lane == 0) { red[wid] = s; red[8 + wid] = s2; }
    __syncthreads();
    if (c == 0) {
        float ts = 0.f, ts2 = 0.f;
#pragma unroll
        for (int i = 0; i < 8; ++i) { ts += red[i]; ts2 += red[8 + i]; }
        const float mu  = ts * (1.f / 512.f);
        const float var = ts2 * (1.f / 512.f) - mu * mu;
        stats[0] = mu;
        stats[1] = rsqrtf(var + LN_EPS);
    }
    __syncthreads();
    const float mu = stats[0], rstd = stats[1];
    xr[((size_t)(b * MTOK + np)) * DIMC + c] = (y - mu) * rstd * lng[c] + lnb[c];
}

// ---------------------------------------------------------------------------
// Masked attention, one thread per query row, online softmax.
// q/k/v/out all stored as (B, tokens, C) with head slice c = h*64+d.
// ---------------------------------------------------------------------------
__global__ __launch_bounds__(128)
void attn_kernel(const float* __restrict__ qb, const float* __restrict__ kb,
                 const float* __restrict__ vb, const void* __restrict__ maskp,
                 const int* __restrict__ flag, float* __restrict__ ob)
{
    const int tid = threadIdx.x;       // 128
    const int gid = blockIdx.x;        // 512 = b*64 + h*8 + nt
    const int nt  = gid & 7;
    const int h   = (gid >> 3) & 7;
    const int b   = gid >> 6;
    const int n   = nt * 128 + tid;
    const float scale = 0.125f;        // 64^-0.5

    const float* qrow = qb + ((size_t)(b * NTOK + n)) * DIMC + h * HD;
    float q[HD];
#pragma unroll
    for (int d4 = 0; d4 < HD; d4 += 4) {
        const float4 t = *(const float4*)(qrow + d4);
        q[d4] = t.x; q[d4 + 1] = t.y; q[d4 + 2] = t.z; q[d4 + 3] = t.w;
    }
    const float* kbh = kb + ((size_t)b * MTOK) * DIMC + h * HD;
    const float* vbh = vb + ((size_t)b * MTOK) * DIMC + h * HD;

    float o[HD];
#pragma unroll
    for (int d = 0; d < HD; ++d) o[d] = 0.f;
    float mx = -1e30f, denom = 0.f;

    const int mtype = *flag;
    const size_t mb = ((size_t)((b * NHEAD + h) * NTOK + n)) * MTOK;
    const int* mi = (const int*)maskp + mb;
    const unsigned char* mu8 = (const unsigned char*)maskp + mb;
    const float* mf = (const float*)maskp + mb;

    for (int m0 = 0; m0 < MTOK; m0 += 4) {
        int mk[4];
        if (mtype == 1) {
            const uchar4 u = *(const uchar4*)(mu8 + m0);
            mk[0] = u.x; mk[1] = u.y; mk[2] = u.z; mk[3] = u.w;
        } else if (mtype == 2) {
            const float4 u = *(const float4*)(mf + m0);
            mk[0] = (u.x != 0.f); mk[1] = (u.y != 0.f);
            mk[2] = (u.z != 0.f); mk[3] = (u.w != 0.f);
        } else {
            const int4 u = *(const int4*)(mi + m0);
            mk[0] = u.x; mk[1] = u.y; mk[2] = u.z; mk[3] = u.w;
        }
#pragma unroll
        for (int j = 0; j < 4; ++j) {
            const int m = m0 + j;
            const float* kr = kbh + (size_t)m * DIMC;
            float s0 = 0.f, s1 = 0.f, s2 = 0.f, s3 = 0.f;
#pragma unroll
            for (int d = 0; d < HD; d += 4) {
                s0 += q[d + 0] * kr[d + 0];
                s1 += q[d + 1] * kr[d + 1];
                s2 += q[d + 2] * kr[d + 2];
                s3 += q[d + 3] * kr[d + 3];
            }
            float s = ((s0 + s1) + (s2 + s3)) * scale;
            if (mk[j]) s = -INFINITY;
            if (s > mx) {                      // rare: ~H(256) times
                const float corr = __expf(mx - s);
                denom *= corr;
#pragma unroll
                for (int d = 0; d < HD; ++d) o[d] *= corr;
                mx = s;
            }
            const float p = __expf(s - mx);    // masked -> exp(-inf)=0
            denom += p;
            const float* vr = vbh + (size_t)m * DIMC;
#pragma unroll
            for (int d = 0; d < HD; ++d) o[d] += p * vr[d];
        }
    }
    const float inv = 1.0f / denom;
    float* orow = ob + ((size_t)(b * NTOK + n)) * DIMC + h * HD;
#pragma unroll
    for (int d4 = 0; d4 < HD; d4 += 4) {
        float4 t;
        t.x = o[d4] * inv; t.y = o[d4 + 1] * inv;
        t.z = o[d4 + 2] * inv; t.w = o[d4 + 3] * inv;
        *(float4*)(orow + d4) = t;
    }
}

// ---------------------------------------------------------------------------
extern "C" void kernel_launch(void* const* d_in, const int* in_sizes, int n_in,
                              void* d_out, int out_size, void* d_ws, size_t ws_size,
                              hipStream_t stream)
{
    const float* x      = (const float*)d_in[0];
    const void*  mask   = d_in[1];
    const float* q_w1   = (const float*)d_in[2];
    const float* q_w2   = (const float*)d_in[3];
    const float* k_w1   = (const float*)d_in[4];
    const float* k_w2   = (const float*)d_in[5];
    const float* v_w1   = (const float*)d_in[6];
    const float* v_w2   = (const float*)d_in[7];
    const float* sr_w   = (const float*)d_in[8];
    const float* sr_b   = (const float*)d_in[9];
    const float* ln_g   = (const float*)d_in[10];
    const float* ln_b   = (const float*)d_in[11];
    const float* proj_w = (const float*)d_in[12];
    const float* proj_b = (const float*)d_in[13];

    float* ws   = (float*)d_ws;
    float* xr   = ws;                                   // 1M floats  (4 MB)
    float* kbuf = ws + (1u << 20);                      // 1M floats
    float* vbuf = ws + (2u << 20);                      // 1M floats
    float* t1   = ws + (3u << 20);                      // 256K floats
    int*   flag = (int*)(ws + (3u << 20) + 262144);     // 1 int
    float* q1   = ws + (4u << 20);                      // 1M floats
    float* ao   = ws + (4u << 20);                      // 4M floats (reuses q1 region after q1 dead)
    float* qbuf = (float*)d_out;                        // q staged in d_out, overwritten by final proj

    detect_mask_kernel<<<1, 1, 0, stream>>>((const unsigned int*)mask, flag);

    // q = (x @ q_w1^T) @ q_w2^T
    gemm_nt<64, 64, 16, 4, 4><<<dim3(2, 128), 256, 0, stream>>>(x, q_w1, nullptr, q1, 8192, 128, 512);
    gemm_nt<128, 128, 16, 8, 8><<<dim3(4, 64), 256, 0, stream>>>(q1, q_w2, nullptr, qbuf, 8192, 512, 128);

    // spatial reduction: depthwise conv 2x2 s2 + LayerNorm
    conv_ln_kernel<<<2048, 512, 0, stream>>>(x, sr_w, sr_b, ln_g, ln_b, xr);

    // k, v low-rank projections (t1 reused sequentially)
    gemm_nt<64, 64, 16, 4, 4><<<dim3(2, 32), 256, 0, stream>>>(xr, k_w1, nullptr, t1, 2048, 128, 512);
    gemm_nt<128, 128, 16, 8, 8><<<dim3(4, 16), 256, 0, stream>>>(t1, k_w2, nullptr, kbuf, 2048, 512, 128);
    gemm_nt<64, 64, 16, 4, 4><<<dim3(2, 32), 256, 0, stream>>>(xr, v_w1, nullptr, t1, 2048, 128, 512);
    gemm_nt<128, 128, 16, 8, 8><<<dim3(4, 16), 256, 0, stream>>>(t1, v_w2, nullptr, vbuf, 2048, 512, 128);

    // masked softmax attention
    attn_kernel<<<512, 128, 0, stream>>>(qbuf, kbuf, vbuf, mask, flag, ao);

    // output projection (+bias)
    gemm_nt<128, 128, 16, 8, 8><<<dim3(4, 64), 256, 0, stream>>>(ao, proj_w, proj_b, (float*)d_out, 8192, 512, 512);
}

// Round 2
// 399.101 us; speedup vs baseline: 1.8458x; 1.8458x over previous
//
#include <hip/hip_runtime.h>
#include <hip/hip_bf16.h>
#include <math.h>
#include <stdint.h>

#define DIMC   512
#define NHEAD  8
#define HD     64
#define NTOK   1024
#define MTOK   256
#define BSZ    8
#define LN_EPS 1e-5f

typedef __attribute__((ext_vector_type(8))) short  short8v;   // 8 bf16 (4 VGPR)
typedef __attribute__((ext_vector_type(4))) float  f32x4;     // MFMA C/D frag
typedef __attribute__((ext_vector_type(4))) unsigned short us4;

__device__ inline unsigned short f2bf(float f) {
    union { float f; unsigned int u; } v; v.f = f;
    unsigned int u = v.u;
    return (unsigned short)((u + 0x7FFFu + ((u >> 16) & 1u)) >> 16);  // RNE, finite inputs
}

// ---------------------------------------------------------------------------
// Mask dtype probe: 0 = int32, 1 = uint8, 2 = float32
// ---------------------------------------------------------------------------
__global__ void detect_mask_kernel(const unsigned int* __restrict__ m,
                                   int* __restrict__ flag)
{
    if (blockIdx.x == 0 && threadIdx.x == 0) {
        int all01 = 1, allf = 1;
        for (int i = 0; i < 64; ++i) {
            unsigned int w = m[i];
            if (w > 1u) all01 = 0;
            if (w != 0u && w != 0x3F800000u) allf = 0;
        }
        *flag = all01 ? 0 : (allf ? 2 : 1);
    }
}

// ---------------------------------------------------------------------------
// fp32 GEMM: C(M,N) = A(M,K) @ B(N,K)^T (+bias). OUT_MODE: 0=f32, 1=bf16,
// 2=bf16 per-batch transposed (V path: rows are b*256+m, out[(b*N+col)*256+m]).
// ---------------------------------------------------------------------------
template<int BM, int BN, int BK, int TM, int TN, int OUT_MODE>
__global__ __launch_bounds__(256)
void gemm_nt(const float* __restrict__ A, const float* __restrict__ B,
             const float* __restrict__ bias, void* __restrict__ Cp,
             int M, int N, int K)
{
    __shared__ __align__(16) float As[BK][BM + 4];
    __shared__ __align__(16) float Bs[BK][BN + 4];
    constexpr int AV = (BM * BK) / (4 * 256);
    constexpr int BV = (BN * BK) / (4 * 256);

    const int tid = threadIdx.x;
    const int tx = tid & 15;
    const int ty = tid >> 4;
    const size_t bm = (size_t)blockIdx.y * BM;
    const size_t bn = (size_t)blockIdx.x * BN;

    float acc[TM][TN];
#pragma unroll
    for (int i = 0; i < TM; ++i)
#pragma unroll
        for (int j = 0; j < TN; ++j) acc[i][j] = 0.f;

    for (int kt = 0; kt < K; kt += BK) {
        float4 ast[AV], bst[BV];
#pragma unroll
        for (int t = 0; t < AV; ++t) {
            const int idx = tid + t * 256;
            const int r = idx >> 2, cc = (idx & 3) * 4;
            ast[t] = *(const float4*)(A + (bm + r) * K + kt + cc);
        }
#pragma unroll
        for (int t = 0; t < BV; ++t) {
            const int idx = tid + t * 256;
            const int r = idx >> 2, cc = (idx & 3) * 4;
            bst[t] = *(const float4*)(B + (bn + r) * K + kt + cc);
        }
        __syncthreads();
#pragma unroll
        for (int t = 0; t < AV; ++t) {
            const int idx = tid + t * 256;
            const int r = idx >> 2, cc = (idx & 3) * 4;
            As[cc + 0][r] = ast[t].x; As[cc + 1][r] = ast[t].y;
            As[cc + 2][r] = ast[t].z; As[cc + 3][r] = ast[t].w;
        }
#pragma unroll
        for (int t = 0; t < BV; ++t) {
            const int idx = tid + t * 256;
            const int r = idx >> 2, cc = (idx & 3) * 4;
            Bs[cc + 0][r] = bst[t].x; Bs[cc + 1][r] = bst[t].y;
            Bs[cc + 2][r] = bst[t].z; Bs[cc + 3][r] = bst[t].w;
        }
        __syncthreads();
#pragma unroll
        for (int kk = 0; kk < BK; ++kk) {
            float a[TM], bb[TN];
#pragma unroll
            for (int i4 = 0; i4 < TM; i4 += 4) {
                const float4 t4 = *(const float4*)(&As[kk][ty * TM + i4]);
                a[i4 + 0] = t4.x; a[i4 + 1] = t4.y; a[i4 + 2] = t4.z; a[i4 + 3] = t4.w;
            }
#pragma unroll
            for (int j4 = 0; j4 < TN; j4 += 4) {
                const float4 t4 = *(const float4*)(&Bs[kk][tx * TN + j4]);
                bb[j4 + 0] = t4.x; bb[j4 + 1] = t4.y; bb[j4 + 2] = t4.z; bb[j4 + 3] = t4.w;
            }
#pragma unroll
            for (int i = 0; i < TM; ++i)
#pragma unroll
                for (int j = 0; j < TN; ++j)
                    acc[i][j] += a[i] * bb[j];
        }
    }

    const size_t col0 = bn + tx * TN;
#pragma unroll
    for (int i = 0; i < TM; ++i) {
        const size_t row = bm + ty * TM + i;
        if (OUT_MODE == 0) {
            float* C = (float*)Cp;
#pragma unroll
            for (int j4 = 0; j4 < TN; j4 += 4) {
                float4 v;
                v.x = acc[i][j4 + 0]; v.y = acc[i][j4 + 1];
                v.z = acc[i][j4 + 2]; v.w = acc[i][j4 + 3];
                if (bias != nullptr) {
                    v.x += bias[col0 + j4 + 0]; v.y += bias[col0 + j4 + 1];
                    v.z += bias[col0 + j4 + 2]; v.w += bias[col0 + j4 + 3];
                }
                *(float4*)(C + row * N + col0 + j4) = v;
            }
        } else if (OUT_MODE == 1) {
            unsigned short* C = (unsigned short*)Cp;
#pragma unroll
            for (int j4 = 0; j4 < TN; j4 += 4) {
                us4 pk;
                pk[0] = f2bf(acc[i][j4 + 0]); pk[1] = f2bf(acc[i][j4 + 1]);
                pk[2] = f2bf(acc[i][j4 + 2]); pk[3] = f2bf(acc[i][j4 + 3]);
                *(us4*)(C + row * N + col0 + j4) = pk;
            }
        } else {
            // per-batch transpose: rows are b*256+m -> C[(b*N + col)*256 + m]
            unsigned short* C = (unsigned short*)Cp;
            const size_t bb_ = row >> 8, mm = row & 255;
#pragma unroll
            for (int j = 0; j < TN; ++j)
                C[(bb_ * N + col0 + j) * 256 + mm] = f2bf(acc[i][j]);
        }
    }
}

// ---------------------------------------------------------------------------
// Fused depthwise 2x2/stride-2 conv + bias + LayerNorm over C.
// ---------------------------------------------------------------------------
__global__ __launch_bounds__(512)
void conv_ln_kernel(const float* __restrict__ x, const float* __restrict__ srw,
                    const float* __restrict__ srb, const float* __restrict__ lng,
                    const float* __restrict__ lnb, float* __restrict__ xr)
{
    const int c  = threadIdx.x;
    const int bn = blockIdx.x;
    const int b  = bn >> 8;
    const int np = bn & 255;
    const int ho = np >> 4, wo = np & 15;
    const int n00 = (ho * 2) * 32 + wo * 2;

    const float* xb = x + ((size_t)b * NTOK) * DIMC + c;
    const float4 w = *(const float4*)(srw + c * 4);
    float y = srb[c]
            + xb[(size_t)(n00     ) * DIMC] * w.x
            + xb[(size_t)(n00 + 1 ) * DIMC] * w.y
            + xb[(size_t)(n00 + 32) * DIMC] * w.z
            + xb[(size_t)(n00 + 33) * DIMC] * w.w;

    float s = y, s2 = y * y;
#pragma unroll
    for (int off = 32; off > 0; off >>= 1) {
        s  += __shfl_down(s,  off);
        s2 += __shfl_down(s2, off);
    }
    __shared__ float red[16];
    __shared__ float stats[2];
    const int lane = c & 63, wid = c >> 6;
    if (lane == 0) { red[wid] = s; red[8 + wid] = s2; }
    __syncthreads();
    if (c == 0) {
        float ts = 0.f, ts2 = 0.f;
#pragma unroll
        for (int i = 0; i < 8; ++i) { ts += red[i]; ts2 += red[8 + i]; }
        const float mu  = ts * (1.f / 512.f);
        const float var = ts2 * (1.f / 512.f) - mu * mu;
        stats[0] = mu;
        stats[1] = rsqrtf(var + LN_EPS);
    }
    __syncthreads();
    const float mu = stats[0], rstd = stats[1];
    xr[((size_t)(b * MTOK + np)) * DIMC + c] = (y - mu) * rstd * lng[c] + lnb[c];
}

// ---------------------------------------------------------------------------
// MFMA attention. Grid: 1024 = bh(64) x qtile(16). Block: 256 = 4 waves.
// Each wave owns 16 query rows x all 256 keys. bf16 in, fp32 accum.
// q: (B,1024,512) bf16. k: (B,256,512) bf16. vt: (B,512,256) bf16 (per-b C-major).
// ---------------------------------------------------------------------------
__global__ __launch_bounds__(256)
void attn_mfma(const unsigned short* __restrict__ qb,
               const unsigned short* __restrict__ kb,
               const unsigned short* __restrict__ vt,
               const void* __restrict__ maskp,
               const int* __restrict__ flag,
               float* __restrict__ ob)
{
    __shared__ unsigned short plds[4 * 16 * 256];   // 32 KB, per-wave P tiles

    const int tid  = threadIdx.x;
    const int w    = tid >> 6;
    const int lane = tid & 63;
    const int g    = lane >> 4;        // 16-lane group 0..3
    const int c16  = lane & 15;
    const int bh   = blockIdx.x >> 4;  // 0..63
    const int qt   = blockIdx.x & 15;
    const int b    = bh >> 3;
    const int h    = bh & 7;
    const int q0   = qt * 64 + w * 16; // wave's first query row

    // ---- Q fragments (A operand): row = c16, k = h*64 + ks*32 + g*8 ----
    short8v qf[2];
#pragma unroll
    for (int ks = 0; ks < 2; ++ks)
        qf[ks] = *(const short8v*)(qb + ((size_t)(b * NTOK + q0 + c16)) * DIMC
                                      + h * HD + ks * 32 + g * 8);

    // ---- S = Q @ K^T : 16 N-frags of 16 keys ----
    f32x4 s[16];
#pragma unroll
    for (int nf = 0; nf < 16; ++nf) s[nf] = (f32x4){0.f, 0.f, 0.f, 0.f};

#pragma unroll
    for (int nf = 0; nf < 16; ++nf) {
#pragma unroll
        for (int ks = 0; ks < 2; ++ks) {
            const short8v kf = *(const short8v*)(kb + ((size_t)(b * MTOK + nf * 16 + c16)) * DIMC
                                                    + h * HD + ks * 32 + g * 8);
            s[nf] = __builtin_amdgcn_mfma_f32_16x16x32_bf16(qf[ks], kf, s[nf], 0, 0, 0);
        }
    }

    // ---- scale + mask ----
    const float scale = 0.125f;
    const int mtype = *flag;
    const size_t mrow0 = ((size_t)bh * NTOK + q0 + g * 4) * MTOK;   // row for reg 0
#pragma unroll
    for (int nf = 0; nf < 16; ++nf) {
        const int key = nf * 16 + c16;
#pragma unroll
        for (int r = 0; r < 4; ++r) {
            const size_t mi = mrow0 + (size_t)r * MTOK + key;
            bool mk;
            if (mtype == 0)      mk = ((const int*)maskp)[mi] != 0;
            else if (mtype == 1) mk = ((const unsigned char*)maskp)[mi] != 0;
            else                 mk = ((const float*)maskp)[mi] != 0.f;
            s[nf][r] = mk ? -INFINITY : s[nf][r] * scale;
        }
    }

    // ---- row softmax (row lives in 16 lanes of group g, reg r) ----
    float mx[4] = {-1e30f, -1e30f, -1e30f, -1e30f};
#pragma unroll
    for (int nf = 0; nf < 16; ++nf)
#pragma unroll
        for (int r = 0; r < 4; ++r) mx[r] = fmaxf(mx[r], s[nf][r]);
#pragma unroll
    for (int off = 8; off >= 1; off >>= 1)
#pragma unroll
        for (int r = 0; r < 4; ++r) mx[r] = fmaxf(mx[r], __shfl_xor(mx[r], off, 64));

    float sm[4] = {0.f, 0.f, 0.f, 0.f};
#pragma unroll
    for (int nf = 0; nf < 16; ++nf)
#pragma unroll
        for (int r = 0; r < 4; ++r) {
            const float p = __expf(s[nf][r] - mx[r]);
            s[nf][r] = p;
            sm[r] += p;
        }
#pragma unroll
    for (int off = 8; off >= 1; off >>= 1)
#pragma unroll
        for (int r = 0; r < 4; ++r) sm[r] += __shfl_xor(sm[r], off, 64);
    float inv[4];
#pragma unroll
    for (int r = 0; r < 4; ++r) inv[r] = 1.0f / sm[r];

    // ---- P -> bf16 -> LDS (swizzled: ushort idx ^ ((row&7)<<3)) ----
    unsigned short* pw = plds + w * 16 * 256;
#pragma unroll
    for (int nf = 0; nf < 16; ++nf) {
        const int key = nf * 16 + c16;
#pragma unroll
        for (int r = 0; r < 4; ++r) {
            const int row = g * 4 + r;
            pw[row * 256 + (key ^ ((row & 7) << 3))] = f2bf(s[nf][r] * inv[r]);
        }
    }

    // ---- O = P @ V : A from LDS, B from vt (contiguous keys) ----
    f32x4 o[4];
#pragma unroll
    for (int df = 0; df < 4; ++df) o[df] = (f32x4){0.f, 0.f, 0.f, 0.f};

    const int prow = c16;
    const unsigned short* pr = pw + prow * 256;
#pragma unroll
    for (int kf = 0; kf < 8; ++kf) {
        const int k0 = kf * 32 + g * 8;
        const short8v pa = *(const short8v*)(pr + (k0 ^ ((prow & 7) << 3)));
#pragma unroll
        for (int df = 0; df < 4; ++df) {
            const short8v vf = *(const short8v*)(vt + ((size_t)(b * DIMC + h * HD + df * 16 + c16)) * MTOK + k0);
            o[df] = __builtin_amdgcn_mfma_f32_16x16x32_bf16(pa, vf, o[df], 0, 0, 0);
        }
    }

    // ---- write O (fp32, coalesced 4B per 16-lane group) ----
#pragma unroll
    for (int df = 0; df < 4; ++df)
#pragma unroll
        for (int r = 0; r < 4; ++r)
            ob[((size_t)(b * NTOK + q0 + g * 4 + r)) * DIMC + h * HD + df * 16 + c16] = o[df][r];
}

// ---------------------------------------------------------------------------
extern "C" void kernel_launch(void* const* d_in, const int* in_sizes, int n_in,
                              void* d_out, int out_size, void* d_ws, size_t ws_size,
                              hipStream_t stream)
{
    const float* x      = (const float*)d_in[0];
    const void*  mask   = d_in[1];
    const float* q_w1   = (const float*)d_in[2];
    const float* q_w2   = (const float*)d_in[3];
    const float* k_w1   = (const float*)d_in[4];
    const float* k_w2   = (const float*)d_in[5];
    const float* v_w1   = (const float*)d_in[6];
    const float* v_w2   = (const float*)d_in[7];
    const float* sr_w   = (const float*)d_in[8];
    const float* sr_b   = (const float*)d_in[9];
    const float* ln_g   = (const float*)d_in[10];
    const float* ln_b   = (const float*)d_in[11];
    const float* proj_w = (const float*)d_in[12];
    const float* proj_b = (const float*)d_in[13];

    float* ws = (float*)d_ws;
    // ao occupies first 16 MB; q1/xr/t1 live inside it (all dead before attn writes ao)
    float* ao   = ws;                         // 4M floats (16 MB)
    float* q1   = ws;                         // 1M floats (dead after q2)
    float* xr   = ws + (1u << 20);            // 1M floats (dead after v1)
    float* t1   = ws + (2u << 20);            // 256K floats (dead after v2)
    unsigned short* qb16 = (unsigned short*)(ws + (4u << 20));          // 8 MB
    unsigned short* kb16 = (unsigned short*)(ws + (6u << 20));          // 2 MB
    unsigned short* vt16 = (unsigned short*)(ws + (6u << 20) + (1u << 20)); // 2 MB (offset in floats: 6M + 0.5M*2... laid out below)
    // simpler explicit byte layout:
    unsigned char* wsb = (unsigned char*)d_ws;
    qb16 = (unsigned short*)(wsb + (16u << 20));   // 16 MB .. 24 MB
    kb16 = (unsigned short*)(wsb + (24u << 20));   // 24 MB .. 26 MB
    vt16 = (unsigned short*)(wsb + (26u << 20));   // 26 MB .. 28 MB
    int* flag = (int*)(wsb + (28u << 20));

    detect_mask_kernel<<<1, 1, 0, stream>>>((const unsigned int*)mask, flag);

    // q = (x @ q_w1^T) @ q_w2^T  -> bf16
    gemm_nt<64, 64, 16, 4, 4, 0><<<dim3(2, 128), 256, 0, stream>>>(x, q_w1, nullptr, q1, 8192, 128, 512);
    gemm_nt<128, 128, 16, 8, 8, 1><<<dim3(4, 64), 256, 0, stream>>>(q1, q_w2, nullptr, qb16, 8192, 512, 128);

    // spatial reduction: depthwise conv 2x2 s2 + LayerNorm
    conv_ln_kernel<<<2048, 512, 0, stream>>>(x, sr_w, sr_b, ln_g, ln_b, xr);

    // k (bf16), v (bf16, per-batch transposed)
    gemm_nt<64, 64, 16, 4, 4, 0><<<dim3(2, 32), 256, 0, stream>>>(xr, k_w1, nullptr, t1, 2048, 128, 512);
    gemm_nt<128, 128, 16, 8, 8, 1><<<dim3(4, 16), 256, 0, stream>>>(t1, k_w2, nullptr, kb16, 2048, 512, 128);
    gemm_nt<64, 64, 16, 4, 4, 0><<<dim3(2, 32), 256, 0, stream>>>(xr, v_w1, nullptr, t1, 2048, 128, 512);
    gemm_nt<128, 128, 16, 8, 8, 2><<<dim3(4, 16), 256, 0, stream>>>(t1, v_w2, nullptr, vt16, 2048, 512, 128);

    // MFMA attention
    attn_mfma<<<1024, 256, 0, stream>>>(qb16, kb16, vt16, mask, flag, ao);

    // output projection (+bias), fp32
    gemm_nt<128, 128, 16, 8, 8, 0><<<dim3(4, 64), 256, 0, stream>>>(ao, proj_w, proj_b, d_out, 8192, 512, 512);
}

// Round 4
// 274.428 us; speedup vs baseline: 2.6843x; 1.4543x over previous
//
#include <hip/hip_runtime.h>
#include <hip/hip_bf16.h>
#include <math.h>
#include <stdint.h>

#define DIMC   512
#define NHEAD  8
#define HD     64
#define NTOK   1024
#define MTOK   256
#define BSZ    8
#define LN_EPS 1e-5f

typedef __attribute__((ext_vector_type(8))) short  short8v;   // 8 bf16 (4 VGPR)
typedef __attribute__((ext_vector_type(4))) float  f32x4;     // MFMA C/D frag
typedef __attribute__((ext_vector_type(4))) unsigned short us4;

typedef const __attribute__((address_space(1))) unsigned int* gas1_t;
typedef __attribute__((address_space(3))) unsigned int*       las3_t;

__device__ __forceinline__ void gload_lds16(const void* g, void* l) {
    __builtin_amdgcn_global_load_lds((gas1_t)g, (las3_t)l, 16, 0, 0);
}

__device__ __forceinline__ unsigned short f2bf(float f) {
    union { float f; unsigned int u; } v; v.f = f;
    unsigned int u = v.u;
    return (unsigned short)((u + 0x7FFFu + ((u >> 16) & 1u)) >> 16);  // RNE, finite
}

// ---------------------------------------------------------------------------
// Mask dtype probe: 0 = int32, 1 = uint8, 2 = float32
// ---------------------------------------------------------------------------
__global__ void detect_mask_kernel(const unsigned int* __restrict__ m,
                                   int* __restrict__ flag)
{
    if (blockIdx.x == 0 && threadIdx.x == 0) {
        int all01 = 1, allf = 1;
        for (int i = 0; i < 64; ++i) {
            unsigned int w = m[i];
            if (w > 1u) all01 = 0;
            if (w != 0u && w != 0x3F800000u) allf = 0;
        }
        *flag = all01 ? 0 : (allf ? 2 : 1);
    }
}

// ---------------------------------------------------------------------------
// fp32 -> bf16 elementwise (float4 / us4 vectorized, grid-stride)
// ---------------------------------------------------------------------------
__global__ __launch_bounds__(256)
void f32_to_bf16_kernel(const float* __restrict__ in, unsigned short* __restrict__ out,
                        int n4)
{
    for (int i = blockIdx.x * 256 + threadIdx.x; i < n4; i += gridDim.x * 256) {
        const float4 v = ((const float4*)in)[i];
        us4 p;
        p[0] = f2bf(v.x); p[1] = f2bf(v.y); p[2] = f2bf(v.z); p[3] = f2bf(v.w);
        ((us4*)out)[i] = p;
    }
}

// ---------------------------------------------------------------------------
// Convert all 7 weight tensors to one contiguous bf16 region.
// Layout (elements): qw1[0], kw1[65536], vw1[131072], qw2[196608],
//                    kw2[262144], vw2[327680], proj[393216..655360)
// Grid: exactly 640 blocks x 256 threads, one float4 per thread.
// ---------------------------------------------------------------------------
__global__ __launch_bounds__(256)
void convert_weights_kernel(const float* __restrict__ qw1, const float* __restrict__ kw1,
                            const float* __restrict__ vw1, const float* __restrict__ qw2,
                            const float* __restrict__ kw2, const float* __restrict__ vw2,
                            const float* __restrict__ pw,  unsigned short* __restrict__ out)
{
    const int e = (blockIdx.x * 256 + threadIdx.x) * 4;   // element index
    const float* src; int off;
    if      (e < 65536)  { src = qw1; off = e; }
    else if (e < 131072) { src = kw1; off = e - 65536; }
    else if (e < 196608) { src = vw1; off = e - 131072; }
    else if (e < 262144) { src = qw2; off = e - 196608; }
    else if (e < 327680) { src = kw2; off = e - 262144; }
    else if (e < 393216) { src = vw2; off = e - 327680; }
    else                 { src = pw;  off = e - 393216; }
    const float4 v = *(const float4*)(src + off);
    us4 p;
    p[0] = f2bf(v.x); p[1] = f2bf(v.y); p[2] = f2bf(v.z); p[3] = f2bf(v.w);
    *(us4*)(out + e) = p;
}

// ---------------------------------------------------------------------------
// bf16 MFMA GEMM: C(M,N) = A(M,K) @ B(N,K)^T. 128x128 tile, BK=64, 4 waves.
// global_load_lds(16B) staging, single-buffer 2-barrier loop (m97 structure).
// OUT_MODE: 0 = f32 (+bias), 1 = bf16, 2 = bf16 per-batch transposed
//           (rows are b*256+m, out[(b*N+col)*256+m]).
// Requires M%128==0, N%128==0, K%64==0.
// ---------------------------------------------------------------------------
template<int OUT_MODE>
__global__ __launch_bounds__(256)
void gemm_bf16(const unsigned short* __restrict__ A,
               const unsigned short* __restrict__ B,
               const float* __restrict__ bias,
               void* __restrict__ Cp, int M, int N, int K)
{
    __shared__ unsigned short As[128 * 64];   // 16 KB
    __shared__ unsigned short Bs[128 * 64];   // 16 KB

    const int tid  = threadIdx.x;
    const int w    = tid >> 6;
    const int lane = tid & 63;
    const int c16  = lane & 15;
    const int g    = lane >> 4;
    const int wr   = w >> 1, wc = w & 1;      // 2x2 wave grid, 64x64 per wave
    const size_t bm = (size_t)blockIdx.y * 128;
    const size_t bn = (size_t)blockIdx.x * 128;

    f32x4 acc[4][4];
#pragma unroll
    for (int i = 0; i < 4; ++i)
#pragma unroll
        for (int j = 0; j < 4; ++j) acc[i][j] = (f32x4){0.f, 0.f, 0.f, 0.f};

    for (int kt = 0; kt < K; kt += 64) {
        __syncthreads();   // previous iteration's LDS reads complete
#pragma unroll
        for (int i = 0; i < 4; ++i) {
            const int o   = (((i * 4 + w) * 64) + lane) * 16;  // byte offset in 16KB tile
            const int row = o >> 7;
            const int col = (o & 127) >> 1;                    // element col
            gload_lds16(A + (bm + row) * K + kt + col, (char*)As + o);
        }
#pragma unroll
        for (int i = 0; i < 4; ++i) {
            const int o   = (((i * 4 + w) * 64) + lane) * 16;
            const int row = o >> 7;
            const int col = (o & 127) >> 1;
            gload_lds16(B + (bn + row) * K + kt + col, (char*)Bs + o);
        }
        __syncthreads();   // vmcnt(0) drain + barrier: tiles ready
#pragma unroll
        for (int kk = 0; kk < 2; ++kk) {
            short8v a[4], bb[4];
#pragma unroll
            for (int mf = 0; mf < 4; ++mf)
                a[mf] = *(const short8v*)(As + (wr * 64 + mf * 16 + c16) * 64 + kk * 32 + g * 8);
#pragma unroll
            for (int nf = 0; nf < 4; ++nf)
                bb[nf] = *(const short8v*)(Bs + (wc * 64 + nf * 16 + c16) * 64 + kk * 32 + g * 8);
#pragma unroll
            for (int mf = 0; mf < 4; ++mf)
#pragma unroll
                for (int nf = 0; nf < 4; ++nf)
                    acc[mf][nf] = __builtin_amdgcn_mfma_f32_16x16x32_bf16(a[mf], bb[nf], acc[mf][nf], 0, 0, 0);
        }
    }

    // epilogue: C/D layout col = lane&15, row = (lane>>4)*4 + reg
#pragma unroll
    for (int mf = 0; mf < 4; ++mf) {
#pragma unroll
        for (int nf = 0; nf < 4; ++nf) {
            const size_t col = bn + wc * 64 + nf * 16 + c16;
            const size_t r0  = bm + wr * 64 + mf * 16 + g * 4;
            if (OUT_MODE == 0) {
                float* C = (float*)Cp;
                const float bv = (bias != nullptr) ? bias[col] : 0.f;
#pragma unroll
                for (int r = 0; r < 4; ++r)
                    C[(r0 + r) * N + col] = acc[mf][nf][r] + bv;
            } else if (OUT_MODE == 1) {
                unsigned short* C = (unsigned short*)Cp;
#pragma unroll
                for (int r = 0; r < 4; ++r)
                    C[(r0 + r) * N + col] = f2bf(acc[mf][nf][r]);
            } else {
                unsigned short* C = (unsigned short*)Cp;
                const size_t b  = r0 >> 8;
                const size_t m0 = r0 & 255;   // multiple of 4
                us4 p;
                p[0] = f2bf(acc[mf][nf][0]); p[1] = f2bf(acc[mf][nf][1]);
                p[2] = f2bf(acc[mf][nf][2]); p[3] = f2bf(acc[mf][nf][3]);
                *(us4*)(C + (b * N + col) * 256 + m0) = p;
            }
        }
    }
}

// ---------------------------------------------------------------------------
// Fused depthwise 2x2/stride-2 conv + bias + LayerNorm over C -> bf16 out.
// ---------------------------------------------------------------------------
__global__ __launch_bounds__(512)
void conv_ln_kernel(const float* __restrict__ x, const float* __restrict__ srw,
                    const float* __restrict__ srb, const float* __restrict__ lng,
                    const float* __restrict__ lnb, unsigned short* __restrict__ xr)
{
    const int c  = threadIdx.x;
    const int bn = blockIdx.x;
    const int b  = bn >> 8;
    const int np = bn & 255;
    const int ho = np >> 4, wo = np & 15;
    const int n00 = (ho * 2) * 32 + wo * 2;

    const float* xb = x + ((size_t)b * NTOK) * DIMC + c;
    const float4 w = *(const float4*)(srw + c * 4);
    float y = srb[c]
            + xb[(size_t)(n00     ) * DIMC] * w.x
            + xb[(size_t)(n00 + 1 ) * DIMC] * w.y
            + xb[(size_t)(n00 + 32) * DIMC] * w.z
            + xb[(size_t)(n00 + 33) * DIMC] * w.w;

    float s = y, s2 = y * y;
#pragma unroll
    for (int off = 32; off > 0; off >>= 1) {
        s  += __shfl_down(s,  off);
        s2 += __shfl_down(s2, off);
    }
    __shared__ float red[16];
    __shared__ float stats[2];
    const int lane = c & 63, wid = c >> 6;
    if (lane == 0) { red[wid] = s; red[8 + wid] = s2; }
    __syncthreads();
    if (c == 0) {
        float ts = 0.f, ts2 = 0.f;
#pragma unroll
        for (int i = 0; i < 8; ++i) { ts += red[i]; ts2 += red[8 + i]; }
        const float mu  = ts * (1.f / 512.f);
        const float var = ts2 * (1.f / 512.f) - mu * mu;
        stats[0] = mu;
        stats[1] = rsqrtf(var + LN_EPS);
    }
    __syncthreads();
    const float mu = stats[0], rstd = stats[1];
    xr[((size_t)(b * MTOK + np)) * DIMC + c] = f2bf((y - mu) * rstd * lng[c] + lnb[c]);
}

// ---------------------------------------------------------------------------
// MFMA attention. Grid: 1024 = qt(16) x bh(64); blockIdx.x = qt*64 + bh so
// the 16 q-tiles of one (b,h) are 64 apart -> same XCD -> K/V L2-resident.
// Block: 256 = 4 waves; wave owns 16 query rows x all 256 keys.
// ---------------------------------------------------------------------------
__global__ __launch_bounds__(256)
void attn_mfma(const unsigned short* __restrict__ qb,
               const unsigned short* __restrict__ kb,
               const unsigned short* __restrict__ vt,
               const void* __restrict__ maskp,
               const int* __restrict__ flag,
               unsigned short* __restrict__ ob)
{
    __shared__ unsigned short plds[4 * 16 * 256];   // 32 KB, per-wave P tiles

    const int tid  = threadIdx.x;
    const int w    = tid >> 6;
    const int lane = tid & 63;
    const int g    = lane >> 4;
    const int c16  = lane & 15;
    const int bh   = blockIdx.x & 63;
    const int qt   = blockIdx.x >> 6;
    const int b    = bh >> 3;
    const int h    = bh & 7;
    const int q0   = qt * 64 + w * 16;

    short8v qf[2];
#pragma unroll
    for (int ks = 0; ks < 2; ++ks)
        qf[ks] = *(const short8v*)(qb + ((size_t)(b * NTOK + q0 + c16)) * DIMC
                                      + h * HD + ks * 32 + g * 8);

    f32x4 s[16];
#pragma unroll
    for (int nf = 0; nf < 16; ++nf) s[nf] = (f32x4){0.f, 0.f, 0.f, 0.f};

#pragma unroll
    for (int nf = 0; nf < 16; ++nf) {
#pragma unroll
        for (int ks = 0; ks < 2; ++ks) {
            const short8v kf = *(const short8v*)(kb + ((size_t)(b * MTOK + nf * 16 + c16)) * DIMC
                                                    + h * HD + ks * 32 + g * 8);
            s[nf] = __builtin_amdgcn_mfma_f32_16x16x32_bf16(qf[ks], kf, s[nf], 0, 0, 0);
        }
    }

    const float scale = 0.125f;
    const int mtype = *flag;
    const size_t mrow0 = ((size_t)bh * NTOK + q0 + g * 4) * MTOK;
#pragma unroll
    for (int nf = 0; nf < 16; ++nf) {
        const int key = nf * 16 + c16;
#pragma unroll
        for (int r = 0; r < 4; ++r) {
            const size_t mi = mrow0 + (size_t)r * MTOK + key;
            bool mk;
            if (mtype == 0)      mk = ((const int*)maskp)[mi] != 0;
            else if (mtype == 1) mk = ((const unsigned char*)maskp)[mi] != 0;
            else                 mk = ((const float*)maskp)[mi] != 0.f;
            s[nf][r] = mk ? -INFINITY : s[nf][r] * scale;
        }
    }

    float mx[4] = {-1e30f, -1e30f, -1e30f, -1e30f};
#pragma unroll
    for (int nf = 0; nf < 16; ++nf)
#pragma unroll
        for (int r = 0; r < 4; ++r) mx[r] = fmaxf(mx[r], s[nf][r]);
#pragma unroll
    for (int off = 8; off >= 1; off >>= 1)
#pragma unroll
        for (int r = 0; r < 4; ++r) mx[r] = fmaxf(mx[r], __shfl_xor(mx[r], off, 64));

    float sm[4] = {0.f, 0.f, 0.f, 0.f};
#pragma unroll
    for (int nf = 0; nf < 16; ++nf)
#pragma unroll
        for (int r = 0; r < 4; ++r) {
            const float p = __expf(s[nf][r] - mx[r]);
            s[nf][r] = p;
            sm[r] += p;
        }
#pragma unroll
    for (int off = 8; off >= 1; off >>= 1)
#pragma unroll
        for (int r = 0; r < 4; ++r) sm[r] += __shfl_xor(sm[r], off, 64);
    float inv[4];
#pragma unroll
    for (int r = 0; r < 4; ++r) inv[r] = 1.0f / sm[r];

    unsigned short* pw = plds + w * 16 * 256;
#pragma unroll
    for (int nf = 0; nf < 16; ++nf) {
        const int key = nf * 16 + c16;
#pragma unroll
        for (int r = 0; r < 4; ++r) {
            const int row = g * 4 + r;
            pw[row * 256 + (key ^ ((row & 7) << 3))] = f2bf(s[nf][r] * inv[r]);
        }
    }

    f32x4 o[4];
#pragma unroll
    for (int df = 0; df < 4; ++df) o[df] = (f32x4){0.f, 0.f, 0.f, 0.f};

    const int prow = c16;
    const unsigned short* pr = pw + prow * 256;
#pragma unroll
    for (int kf = 0; kf < 8; ++kf) {
        const int k0 = kf * 32 + g * 8;
        const short8v pa = *(const short8v*)(pr + (k0 ^ ((prow & 7) << 3)));
#pragma unroll
        for (int df = 0; df < 4; ++df) {
            const short8v vf = *(const short8v*)(vt + ((size_t)(b * DIMC + h * HD + df * 16 + c16)) * MTOK + k0);
            o[df] = __builtin_amdgcn_mfma_f32_16x16x32_bf16(pa, vf, o[df], 0, 0, 0);
        }
    }

#pragma unroll
    for (int df = 0; df < 4; ++df)
#pragma unroll
        for (int r = 0; r < 4; ++r)
            ob[((size_t)(b * NTOK + q0 + g * 4 + r)) * DIMC + h * HD + df * 16 + c16] =
                f2bf(o[df][r]);
}

// ---------------------------------------------------------------------------
extern "C" void kernel_launch(void* const* d_in, const int* in_sizes, int n_in,
                              void* d_out, int out_size, void* d_ws, size_t ws_size,
                              hipStream_t stream)
{
    const float* x      = (const float*)d_in[0];
    const void*  mask   = d_in[1];
    const float* q_w1   = (const float*)d_in[2];
    const float* q_w2   = (const float*)d_in[3];
    const float* k_w1   = (const float*)d_in[4];
    const float* k_w2   = (const float*)d_in[5];
    const float* v_w1   = (const float*)d_in[6];
    const float* v_w2   = (const float*)d_in[7];
    const float* sr_w   = (const float*)d_in[8];
    const float* sr_b   = (const float*)d_in[9];
    const float* ln_g   = (const float*)d_in[10];
    const float* ln_b   = (const float*)d_in[11];
    const float* proj_w = (const float*)d_in[12];
    const float* proj_b = (const float*)d_in[13];

    unsigned char* wsb = (unsigned char*)d_ws;
    unsigned short* xb16 = (unsigned short*)(wsb + 0);              // 8MB (dead after q1 gemm)
    unsigned short* ao16 = (unsigned short*)(wsb + 0);              // 8MB (reuses xb16)
    unsigned short* qb16 = (unsigned short*)(wsb + (8u  << 20));    // 8MB
    unsigned short* q1b  = (unsigned short*)(wsb + (16u << 20));    // 2MB
    unsigned short* xrb  = (unsigned short*)(wsb + (18u << 20));    // 2MB
    unsigned short* t1k  = (unsigned short*)(wsb + (20u << 20));    // 512KB
    unsigned short* t1v  = (unsigned short*)(wsb + (20u << 20) + (512u << 10));
    unsigned short* kb16 = (unsigned short*)(wsb + (21u << 20));    // 2MB
    unsigned short* vt16 = (unsigned short*)(wsb + (23u << 20));    // 2MB
    unsigned short* wts  = (unsigned short*)(wsb + (25u << 20));    // 1.25MB
    int*            flag = (int*)(wsb + (27u << 20));

    const int QW1 = 0, KW1 = 65536, VW1 = 131072, QW2 = 196608,
              KW2 = 262144, VW2 = 327680, PW = 393216;

    detect_mask_kernel<<<1, 1, 0, stream>>>((const unsigned int*)mask, flag);
    convert_weights_kernel<<<640, 256, 0, stream>>>(q_w1, k_w1, v_w1, q_w2, k_w2, v_w2,
                                                    proj_w, wts);
    f32_to_bf16_kernel<<<2048, 256, 0, stream>>>(x, xb16, 1048576);
    conv_ln_kernel<<<2048, 512, 0, stream>>>(x, sr_w, sr_b, ln_g, ln_b, xrb);

    // q = (x @ q_w1^T) @ q_w2^T   (all bf16 MFMA)
    gemm_bf16<1><<<dim3(1, 64), 256, 0, stream>>>(xb16, wts + QW1, nullptr, q1b,  8192, 128, 512);
    gemm_bf16<1><<<dim3(4, 64), 256, 0, stream>>>(q1b,  wts + QW2, nullptr, qb16, 8192, 512, 128);

    // k, v from reduced tokens
    gemm_bf16<1><<<dim3(1, 16), 256, 0, stream>>>(xrb, wts + KW1, nullptr, t1k,  2048, 128, 512);
    gemm_bf16<1><<<dim3(4, 16), 256, 0, stream>>>(t1k, wts + KW2, nullptr, kb16, 2048, 512, 128);
    gemm_bf16<1><<<dim3(1, 16), 256, 0, stream>>>(xrb, wts + VW1, nullptr, t1v,  2048, 128, 512);
    gemm_bf16<2><<<dim3(4, 16), 256, 0, stream>>>(t1v, wts + VW2, nullptr, vt16, 2048, 512, 128);

    // MFMA attention -> bf16 ao
    attn_mfma<<<1024, 256, 0, stream>>>(qb16, kb16, vt16, mask, flag, ao16);

    // output projection (+bias), bf16 MFMA, fp32 out
    gemm_bf16<0><<<dim3(4, 64), 256, 0, stream>>>(ao16, wts + PW, proj_b, d_out, 8192, 512, 512);
}

// Round 5
// 240.929 us; speedup vs baseline: 3.0576x; 1.1390x over previous
//
#include <hip/hip_runtime.h>
#include <hip/hip_bf16.h>
#include <math.h>
#include <stdint.h>

#define DIMC   512
#define NHEAD  8
#define HD     64
#define NTOK   1024
#define MTOK   256
#define BSZ    8
#define LN_EPS 1e-5f

typedef __attribute__((ext_vector_type(8))) short  short8v;   // 8 bf16 (4 VGPR)
typedef __attribute__((ext_vector_type(4))) float  f32x4;     // MFMA C/D frag
typedef __attribute__((ext_vector_type(4))) unsigned short us4;

typedef const __attribute__((address_space(1))) unsigned int* gas1_t;
typedef __attribute__((address_space(3))) unsigned int*       las3_t;

__device__ __forceinline__ void gload_lds16(const void* g, void* l) {
    __builtin_amdgcn_global_load_lds((gas1_t)g, (las3_t)l, 16, 0, 0);
}

__device__ __forceinline__ unsigned short f2bf(float f) {
    union { float f; unsigned int u; } v; v.f = f;
    unsigned int u = v.u;
    return (unsigned short)((u + 0x7FFFu + ((u >> 16) & 1u)) >> 16);  // RNE, finite
}

// ---------------------------------------------------------------------------
// Mask dtype probe: 0 = int32, 1 = uint8, 2 = float32
// ---------------------------------------------------------------------------
__global__ void detect_mask_kernel(const unsigned int* __restrict__ m,
                                   int* __restrict__ flag)
{
    if (blockIdx.x == 0 && threadIdx.x == 0) {
        int all01 = 1, allf = 1;
        for (int i = 0; i < 64; ++i) {
            unsigned int w = m[i];
            if (w > 1u) all01 = 0;
            if (w != 0u && w != 0x3F800000u) allf = 0;
        }
        *flag = all01 ? 0 : (allf ? 2 : 1);
    }
}

// ---------------------------------------------------------------------------
// Bit-pack the (B,H,N,M) mask: per 256-key row -> 4 uint64 words.
// Wave handles one row: lane l loads keys 4l..4l+3; ballot j packs
// bit l = mask[4l+j]. Attn reads word (c16&3), bit (nf*4 + (c16>>2)).
// Grid: 16384 blocks x 256 thr (4 waves = 4 rows/block). Coalesced.
// ---------------------------------------------------------------------------
__global__ __launch_bounds__(256)
void pack_mask_kernel(const void* __restrict__ maskp, const int* __restrict__ flag,
                      unsigned long long* __restrict__ packed)
{
    const int w = threadIdx.x >> 6, lane = threadIdx.x & 63;
    const long long row = (long long)blockIdx.x * 4 + w;   // 65536 rows
    const int mtype = *flag;
    int m0, m1, m2, m3;
    if (mtype == 0) {
        const int4 v = ((const int4*)maskp)[row * 64 + lane];
        m0 = v.x; m1 = v.y; m2 = v.z; m3 = v.w;
    } else if (mtype == 1) {
        const uchar4 v = ((const uchar4*)maskp)[row * 64 + lane];
        m0 = v.x; m1 = v.y; m2 = v.z; m3 = v.w;
    } else {
        const float4 v = ((const float4*)maskp)[row * 64 + lane];
        m0 = (v.x != 0.f); m1 = (v.y != 0.f); m2 = (v.z != 0.f); m3 = (v.w != 0.f);
    }
    const unsigned long long b0 = __ballot(m0 != 0);
    const unsigned long long b1 = __ballot(m1 != 0);
    const unsigned long long b2 = __ballot(m2 != 0);
    const unsigned long long b3 = __ballot(m3 != 0);
    if (lane < 4) {
        const unsigned long long v = lane == 0 ? b0 : lane == 1 ? b1
                                   : lane == 2 ? b2 : b3;
        packed[row * 4 + lane] = v;
    }
}

// ---------------------------------------------------------------------------
// fp32 -> bf16 elementwise (float4 / us4 vectorized, grid-stride)
// ---------------------------------------------------------------------------
__global__ __launch_bounds__(256)
void f32_to_bf16_kernel(const float* __restrict__ in, unsigned short* __restrict__ out,
                        int n4)
{
    for (int i = blockIdx.x * 256 + threadIdx.x; i < n4; i += gridDim.x * 256) {
        const float4 v = ((const float4*)in)[i];
        us4 p;
        p[0] = f2bf(v.x); p[1] = f2bf(v.y); p[2] = f2bf(v.z); p[3] = f2bf(v.w);
        ((us4*)out)[i] = p;
    }
}

// ---------------------------------------------------------------------------
// Convert all 7 weight tensors to one contiguous bf16 region; additionally
// emit transposed copies of the three w1 matrices (for the combine gemm).
// Layout (elements): qw1[0], kw1[65536], vw1[131072], qw2[196608],
//                    kw2[262144], vw2[327680], proj[393216..655360)
// w1t: three (512x128) matrices, 65536 elements each.
// Grid: exactly 640 blocks x 256 threads, one float4 per thread.
// ---------------------------------------------------------------------------
__global__ __launch_bounds__(256)
void convert_weights_kernel(const float* __restrict__ qw1, const float* __restrict__ kw1,
                            const float* __restrict__ vw1, const float* __restrict__ qw2,
                            const float* __restrict__ kw2, const float* __restrict__ vw2,
                            const float* __restrict__ pw,  unsigned short* __restrict__ out,
                            unsigned short* __restrict__ w1t)
{
    const int e = (blockIdx.x * 256 + threadIdx.x) * 4;   // element index
    const float* src; int off;
    if      (e < 65536)  { src = qw1; off = e; }
    else if (e < 131072) { src = kw1; off = e - 65536; }
    else if (e < 196608) { src = vw1; off = e - 131072; }
    else if (e < 262144) { src = qw2; off = e - 196608; }
    else if (e < 327680) { src = kw2; off = e - 262144; }
    else if (e < 393216) { src = vw2; off = e - 327680; }
    else                 { src = pw;  off = e - 393216; }
    const float4 v = *(const float4*)(src + off);
    us4 p;
    p[0] = f2bf(v.x); p[1] = f2bf(v.y); p[2] = f2bf(v.z); p[3] = f2bf(v.w);
    *(us4*)(out + e) = p;
    if (e < 196608) {   // w1 family: also store transposed (j,k) <- (k,j)
        const int mat = e >> 16, rem = e & 65535;
        const int k = rem >> 9, j = rem & 511;
#pragma unroll
        for (int t = 0; t < 4; ++t)
            w1t[mat * 65536 + (j + t) * 128 + k] = p[t];
    }
}

// ---------------------------------------------------------------------------
// bf16 MFMA GEMM: C(M,N) = A(M,K) @ B(N,K)^T. 128x128 tile, BK=64, 4 waves.
// global_load_lds(16B) staging, single-buffer 2-barrier loop (m97 structure).
// OUT_MODE: 0 = f32 (+bias), 1 = bf16,
//           2 = bf16 per-batch transposed (rows b*256+m -> C[(b*N+col)*256+m]),
//           3 = kv split: col<512 -> k bf16 row-major (ld 512) into Cp;
//               col>=512 -> v bf16 per-batch transposed into Cp+1048576 elems
//               (layout contract: vt16 buffer sits 2 MB after kb16).
// BSEL: B += (bm>>9)*65536 (per-512-row-block B matrix select, combine gemm).
// Requires M%128==0, N%128==0, K%64==0.
// ---------------------------------------------------------------------------
template<int OUT_MODE, int BSEL>
__global__ __launch_bounds__(256)
void gemm_bf16(const unsigned short* __restrict__ A,
               const unsigned short* __restrict__ B,
               const float* __restrict__ bias,
               void* __restrict__ Cp, int M, int N, int K)
{
    __shared__ unsigned short As[128 * 64];   // 16 KB
    __shared__ unsigned short Bs[128 * 64];   // 16 KB

    const int tid  = threadIdx.x;
    const int w    = tid >> 6;
    const int lane = tid & 63;
    const int c16  = lane & 15;
    const int g    = lane >> 4;
    const int wr   = w >> 1, wc = w & 1;      // 2x2 wave grid, 64x64 per wave
    const size_t bm = (size_t)blockIdx.y * 128;
    const size_t bn = (size_t)blockIdx.x * 128;
    if (BSEL) B += (bm >> 9) * 65536;

    f32x4 acc[4][4];
#pragma unroll
    for (int i = 0; i < 4; ++i)
#pragma unroll
        for (int j = 0; j < 4; ++j) acc[i][j] = (f32x4){0.f, 0.f, 0.f, 0.f};

    for (int kt = 0; kt < K; kt += 64) {
        __syncthreads();   // previous iteration's LDS reads complete
#pragma unroll
        for (int i = 0; i < 4; ++i) {
            const int o   = (((i * 4 + w) * 64) + lane) * 16;  // byte offset in 16KB tile
            const int row = o >> 7;
            const int col = (o & 127) >> 1;                    // element col
            gload_lds16(A + (bm + row) * K + kt + col, (char*)As + o);
        }
#pragma unroll
        for (int i = 0; i < 4; ++i) {
            const int o   = (((i * 4 + w) * 64) + lane) * 16;
            const int row = o >> 7;
            const int col = (o & 127) >> 1;
            gload_lds16(B + (bn + row) * K + kt + col, (char*)Bs + o);
        }
        __syncthreads();   // vmcnt(0) drain + barrier: tiles ready
#pragma unroll
        for (int kk = 0; kk < 2; ++kk) {
            short8v a[4], bb[4];
#pragma unroll
            for (int mf = 0; mf < 4; ++mf)
                a[mf] = *(const short8v*)(As + (wr * 64 + mf * 16 + c16) * 64 + kk * 32 + g * 8);
#pragma unroll
            for (int nf = 0; nf < 4; ++nf)
                bb[nf] = *(const short8v*)(Bs + (wc * 64 + nf * 16 + c16) * 64 + kk * 32 + g * 8);
#pragma unroll
            for (int mf = 0; mf < 4; ++mf)
#pragma unroll
                for (int nf = 0; nf < 4; ++nf)
                    acc[mf][nf] = __builtin_amdgcn_mfma_f32_16x16x32_bf16(a[mf], bb[nf], acc[mf][nf], 0, 0, 0);
        }
    }

    // epilogue: C/D layout col = lane&15, row = (lane>>4)*4 + reg
#pragma unroll
    for (int mf = 0; mf < 4; ++mf) {
#pragma unroll
        for (int nf = 0; nf < 4; ++nf) {
            const size_t col = bn + wc * 64 + nf * 16 + c16;
            const size_t r0  = bm + wr * 64 + mf * 16 + g * 4;
            if (OUT_MODE == 0) {
                float* C = (float*)Cp;
                const float bv = (bias != nullptr) ? bias[col] : 0.f;
#pragma unroll
                for (int r = 0; r < 4; ++r)
                    C[(r0 + r) * N + col] = acc[mf][nf][r] + bv;
            } else if (OUT_MODE == 1) {
                unsigned short* C = (unsigned short*)Cp;
#pragma unroll
                for (int r = 0; r < 4; ++r)
                    C[(r0 + r) * N + col] = f2bf(acc[mf][nf][r]);
            } else if (OUT_MODE == 2) {
                unsigned short* C = (unsigned short*)Cp;
                const size_t b  = r0 >> 8;
                const size_t m0 = r0 & 255;   // multiple of 4
                us4 p;
                p[0] = f2bf(acc[mf][nf][0]); p[1] = f2bf(acc[mf][nf][1]);
                p[2] = f2bf(acc[mf][nf][2]); p[3] = f2bf(acc[mf][nf][3]);
                *(us4*)(C + (b * N + col) * 256 + m0) = p;
            } else {
                if (col < 512) {
                    unsigned short* Ck = (unsigned short*)Cp;
#pragma unroll
                    for (int r = 0; r < 4; ++r)
                        Ck[(r0 + r) * 512 + col] = f2bf(acc[mf][nf][r]);
                } else {
                    unsigned short* Cv = (unsigned short*)Cp + 1048576;  // vt16
                    const size_t b  = r0 >> 8;
                    const size_t m0 = r0 & 255;
                    us4 p;
                    p[0] = f2bf(acc[mf][nf][0]); p[1] = f2bf(acc[mf][nf][1]);
                    p[2] = f2bf(acc[mf][nf][2]); p[3] = f2bf(acc[mf][nf][3]);
                    *(us4*)(Cv + (b * 512 + (col - 512)) * 256 + m0) = p;
                }
            }
        }
    }
}

// ---------------------------------------------------------------------------
// Fused depthwise 2x2/stride-2 conv + bias + LayerNorm over C -> bf16 out.
// ---------------------------------------------------------------------------
__global__ __launch_bounds__(512)
void conv_ln_kernel(const float* __restrict__ x, const float* __restrict__ srw,
                    const float* __restrict__ srb, const float* __restrict__ lng,
                    const float* __restrict__ lnb, unsigned short* __restrict__ xr)
{
    const int c  = threadIdx.x;
    const int bn = blockIdx.x;
    const int b  = bn >> 8;
    const int np = bn & 255;
    const int ho = np >> 4, wo = np & 15;
    const int n00 = (ho * 2) * 32 + wo * 2;

    const float* xb = x + ((size_t)b * NTOK) * DIMC + c;
    const float4 w = *(const float4*)(srw + c * 4);
    float y = srb[c]
            + xb[(size_t)(n00     ) * DIMC] * w.x
            + xb[(size_t)(n00 + 1 ) * DIMC] * w.y
            + xb[(size_t)(n00 + 32) * DIMC] * w.z
            + xb[(size_t)(n00 + 33) * DIMC] * w.w;

    float s = y, s2 = y * y;
#pragma unroll
    for (int off = 32; off > 0; off >>= 1) {
        s  += __shfl_down(s,  off);
        s2 += __shfl_down(s2, off);
    }
    __shared__ float red[16];
    __shared__ float stats[2];
    const int lane = c & 63, wid = c >> 6;
    if (lane == 0) { red[wid] = s; red[8 + wid] = s2; }
    __syncthreads();
    if (c == 0) {
        float ts = 0.f, ts2 = 0.f;
#pragma unroll
        for (int i = 0; i < 8; ++i) { ts += red[i]; ts2 += red[8 + i]; }
        const float mu  = ts * (1.f / 512.f);
        const float var = ts2 * (1.f / 512.f) - mu * mu;
        stats[0] = mu;
        stats[1] = rsqrtf(var + LN_EPS);
    }
    __syncthreads();
    const float mu = stats[0], rstd = stats[1];
    xr[((size_t)(b * MTOK + np)) * DIMC + c] = f2bf((y - mu) * rstd * lng[c] + lnb[c]);
}

// ---------------------------------------------------------------------------
// MFMA attention. Grid: 1024 = qt(16) x bh(64); blockIdx.x = qt*64 + bh so
// the 16 q-tiles of one (b,h) are 64 apart -> same XCD -> K/V L2-resident.
// Block: 256 = 4 waves; wave owns 16 query rows x all 256 keys.
// Mask comes bit-packed: 4 uint64 words per row; this thread's 64 mask bits
// live in word (c16&3), bits nf*4 + (c16>>2).
// ---------------------------------------------------------------------------
__global__ __launch_bounds__(256)
void attn_mfma(const unsigned short* __restrict__ qb,
               const unsigned short* __restrict__ kb,
               const unsigned short* __restrict__ vt,
               const unsigned long long* __restrict__ pmask,
               unsigned short* __restrict__ ob)
{
    __shared__ unsigned short plds[4 * 16 * 256];   // 32 KB, per-wave P tiles

    const int tid  = threadIdx.x;
    const int w    = tid >> 6;
    const int lane = tid & 63;
    const int g    = lane >> 4;
    const int c16  = lane & 15;
    const int bh   = blockIdx.x & 63;
    const int qt   = blockIdx.x >> 6;
    const int b    = bh >> 3;
    const int h    = bh & 7;
    const int q0   = qt * 64 + w * 16;

    // mask words first (latency hides under QK^T MFMAs)
    const size_t prow = (size_t)bh * NTOK + q0 + g * 4;
    unsigned mlo[4], mhi[4];
#pragma unroll
    for (int r = 0; r < 4; ++r) {
        const unsigned long long pm = pmask[(prow + r) * 4 + (c16 & 3)] >> (c16 >> 2);
        mlo[r] = (unsigned)pm;
        mhi[r] = (unsigned)(pm >> 32);
    }

    short8v qf[2];
#pragma unroll
    for (int ks = 0; ks < 2; ++ks)
        qf[ks] = *(const short8v*)(qb + ((size_t)(b * NTOK + q0 + c16)) * DIMC
                                      + h * HD + ks * 32 + g * 8);

    f32x4 s[16];
#pragma unroll
    for (int nf = 0; nf < 16; ++nf) s[nf] = (f32x4){0.f, 0.f, 0.f, 0.f};

#pragma unroll
    for (int nf = 0; nf < 16; ++nf) {
#pragma unroll
        for (int ks = 0; ks < 2; ++ks) {
            const short8v kf = *(const short8v*)(kb + ((size_t)(b * MTOK + nf * 16 + c16)) * DIMC
                                                    + h * HD + ks * 32 + g * 8);
            s[nf] = __builtin_amdgcn_mfma_f32_16x16x32_bf16(qf[ks], kf, s[nf], 0, 0, 0);
        }
    }

    const float scale = 0.125f;
#pragma unroll
    for (int nf = 0; nf < 16; ++nf) {
#pragma unroll
        for (int r = 0; r < 4; ++r) {
            const unsigned bit = ((nf < 8 ? (mlo[r] >> (nf * 4))
                                          : (mhi[r] >> ((nf - 8) * 4))) & 1u);
            s[nf][r] = bit ? -INFINITY : s[nf][r] * scale;
        }
    }

    float mx[4] = {-1e30f, -1e30f, -1e30f, -1e30f};
#pragma unroll
    for (int nf = 0; nf < 16; ++nf)
#pragma unroll
        for (int r = 0; r < 4; ++r) mx[r] = fmaxf(mx[r], s[nf][r]);
#pragma unroll
    for (int off = 8; off >= 1; off >>= 1)
#pragma unroll
        for (int r = 0; r < 4; ++r) mx[r] = fmaxf(mx[r], __shfl_xor(mx[r], off, 64));

    float sm[4] = {0.f, 0.f, 0.f, 0.f};
#pragma unroll
    for (int nf = 0; nf < 16; ++nf)
#pragma unroll
        for (int r = 0; r < 4; ++r) {
            const float p = __expf(s[nf][r] - mx[r]);
            s[nf][r] = p;
            sm[r] += p;
        }
#pragma unroll
    for (int off = 8; off >= 1; off >>= 1)
#pragma unroll
        for (int r = 0; r < 4; ++r) sm[r] += __shfl_xor(sm[r], off, 64);
    float inv[4];
#pragma unroll
    for (int r = 0; r < 4; ++r) inv[r] = 1.0f / sm[r];

    unsigned short* pw = plds + w * 16 * 256;
#pragma unroll
    for (int nf = 0; nf < 16; ++nf) {
        const int key = nf * 16 + c16;
#pragma unroll
        for (int r = 0; r < 4; ++r) {
            const int row = g * 4 + r;
            pw[row * 256 + (key ^ ((row & 7) << 3))] = f2bf(s[nf][r] * inv[r]);
        }
    }

    f32x4 o[4];
#pragma unroll
    for (int df = 0; df < 4; ++df) o[df] = (f32x4){0.f, 0.f, 0.f, 0.f};

    const int prw = c16;
    const unsigned short* pr = pw + prw * 256;
#pragma unroll
    for (int kf = 0; kf < 8; ++kf) {
        const int k0 = kf * 32 + g * 8;
        const short8v pa = *(const short8v*)(pr + (k0 ^ ((prw & 7) << 3)));
#pragma unroll
        for (int df = 0; df < 4; ++df) {
            const short8v vf = *(const short8v*)(vt + ((size_t)(b * DIMC + h * HD + df * 16 + c16)) * MTOK + k0);
            o[df] = __builtin_amdgcn_mfma_f32_16x16x32_bf16(pa, vf, o[df], 0, 0, 0);
        }
    }

#pragma unroll
    for (int df = 0; df < 4; ++df)
#pragma unroll
        for (int r = 0; r < 4; ++r)
            ob[((size_t)(b * NTOK + q0 + g * 4 + r)) * DIMC + h * HD + df * 16 + c16] =
                f2bf(o[df][r]);
}

// ---------------------------------------------------------------------------
extern "C" void kernel_launch(void* const* d_in, const int* in_sizes, int n_in,
                              void* d_out, int out_size, void* d_ws, size_t ws_size,
                              hipStream_t stream)
{
    const float* x      = (const float*)d_in[0];
    const void*  mask   = d_in[1];
    const float* q_w1   = (const float*)d_in[2];
    const float* q_w2   = (const float*)d_in[3];
    const float* k_w1   = (const float*)d_in[4];
    const float* k_w2   = (const float*)d_in[5];
    const float* v_w1   = (const float*)d_in[6];
    const float* v_w2   = (const float*)d_in[7];
    const float* sr_w   = (const float*)d_in[8];
    const float* sr_b   = (const float*)d_in[9];
    const float* ln_g   = (const float*)d_in[10];
    const float* ln_b   = (const float*)d_in[11];
    const float* proj_w = (const float*)d_in[12];
    const float* proj_b = (const float*)d_in[13];

    unsigned char* wsb = (unsigned char*)d_ws;
    unsigned short* xb16 = (unsigned short*)(wsb + 0);              // 8MB (dead after q gemm)
    unsigned short* ao16 = (unsigned short*)(wsb + 0);              // 8MB (reuses xb16)
    unsigned short* qb16 = (unsigned short*)(wsb + (8u  << 20));    // 8MB
    unsigned short* xrb  = (unsigned short*)(wsb + (16u << 20));    // 2MB
    unsigned short* w1t  = (unsigned short*)(wsb + (18u << 20));    // 384KB
    unsigned short* kb16 = (unsigned short*)(wsb + (19u << 20));    // 2MB
    unsigned short* vt16 = (unsigned short*)(wsb + (21u << 20));    // 2MB (= kb16 + 1048576 elems, mode-3 contract)
    unsigned short* wts  = (unsigned short*)(wsb + (23u << 20));    // 1.25MB
    unsigned short* wc16 = (unsigned short*)(wsb + (25u << 20));    // 1.5MB (combined 1536x512)
    unsigned long long* pmask = (unsigned long long*)(wsb + (27u << 20)); // 2MB
    int*            flag = (int*)(wsb + (29u << 20));

    const int QW2 = 196608, PW = 393216;

    detect_mask_kernel<<<1, 1, 0, stream>>>((const unsigned int*)mask, flag);
    pack_mask_kernel<<<16384, 256, 0, stream>>>(mask, flag, pmask);
    convert_weights_kernel<<<640, 256, 0, stream>>>(q_w1, k_w1, v_w1, q_w2, k_w2, v_w2,
                                                    proj_w, wts, w1t);
    f32_to_bf16_kernel<<<2048, 256, 0, stream>>>(x, xb16, 1048576);
    conv_ln_kernel<<<2048, 512, 0, stream>>>(x, sr_w, sr_b, ln_g, ln_b, xrb);

    // combined low-rank weights: WC(1536x512) = [q_w2;k_w2;v_w2] @ w1 (B select per 512 rows)
    gemm_bf16<1, 1><<<dim3(4, 12), 256, 0, stream>>>(wts + QW2, w1t, nullptr, wc16, 1536, 512, 128);

    // q = x @ Wq^T  (8192x512x512)
    gemm_bf16<1, 0><<<dim3(4, 64), 256, 0, stream>>>(xb16, wc16, nullptr, qb16, 8192, 512, 512);

    // [k | v] = xr @ [Wk;Wv]^T  (2048x1024x512), split epilogue k / v-transposed
    gemm_bf16<3, 0><<<dim3(8, 16), 256, 0, stream>>>(xrb, wc16 + 262144, nullptr, kb16, 2048, 1024, 512);

    // MFMA attention -> bf16 ao
    attn_mfma<<<1024, 256, 0, stream>>>(qb16, kb16, vt16, pmask, ao16);

    // output projection (+bias), bf16 MFMA, fp32 out
    gemm_bf16<0, 0><<<dim3(4, 64), 256, 0, stream>>>(ao16, wts + PW, proj_b, d_out, 8192, 512, 512);
}

// Round 6
// 220.596 us; speedup vs baseline: 3.3394x; 1.0922x over previous
//
#include <hip/hip_runtime.h>
#include <hip/hip_bf16.h>
#include <math.h>
#include <stdint.h>

#define DIMC   512
#define NHEAD  8
#define HD     64
#define NTOK   1024
#define MTOK   256
#define BSZ    8
#define LN_EPS 1e-5f

typedef __attribute__((ext_vector_type(8))) short  short8v;   // 8 bf16 (4 VGPR)
typedef __attribute__((ext_vector_type(4))) float  f32x4;     // MFMA C/D frag
typedef __attribute__((ext_vector_type(4))) unsigned short us4;

typedef const __attribute__((address_space(1))) unsigned int* gas1_t;
typedef __attribute__((address_space(3))) unsigned int*       las3_t;

__device__ __forceinline__ void gload_lds16(const void* g, void* l) {
    __builtin_amdgcn_global_load_lds((gas1_t)g, (las3_t)l, 16, 0, 0);
}

__device__ __forceinline__ unsigned short f2bf(float f) {
    union { float f; unsigned int u; } v; v.f = f;
    unsigned int u = v.u;
    return (unsigned short)((u + 0x7FFFu + ((u >> 16) & 1u)) >> 16);  // RNE, finite
}

// ---------------------------------------------------------------------------
// Mask dtype probe (one wave): 0 = int32, 1 = uint8, 2 = float32
// ---------------------------------------------------------------------------
__global__ void detect_mask_kernel(const unsigned int* __restrict__ m,
                                   int* __restrict__ flag)
{
    const int lane = threadIdx.x & 63;
    const unsigned int w = m[lane];
    const unsigned long long not01 = __ballot(w > 1u);
    const unsigned long long notf  = __ballot(w != 0u && w != 0x3F800000u);
    if (lane == 0) *flag = (not01 == 0ull) ? 0 : ((notf == 0ull) ? 2 : 1);
}

// ---------------------------------------------------------------------------
// Bit-pack the (B,H,N,M) mask: per 256-key row -> 4 uint64 words.
// Wave handles one row: lane l loads keys 4l..4l+3; ballot j packs
// bit l = mask[4l+j]. Attn reads word (c16&3), bit (nf*4 + (c16>>2)).
// ---------------------------------------------------------------------------
__global__ __launch_bounds__(256)
void pack_mask_kernel(const void* __restrict__ maskp, const int* __restrict__ flag,
                      unsigned long long* __restrict__ packed)
{
    const int w = threadIdx.x >> 6, lane = threadIdx.x & 63;
    const long long row = (long long)blockIdx.x * 4 + w;   // 65536 rows
    const int mtype = *flag;
    int m0, m1, m2, m3;
    if (mtype == 0) {
        const int4 v = ((const int4*)maskp)[row * 64 + lane];
        m0 = v.x; m1 = v.y; m2 = v.z; m3 = v.w;
    } else if (mtype == 1) {
        const uchar4 v = ((const uchar4*)maskp)[row * 64 + lane];
        m0 = v.x; m1 = v.y; m2 = v.z; m3 = v.w;
    } else {
        const float4 v = ((const float4*)maskp)[row * 64 + lane];
        m0 = (v.x != 0.f); m1 = (v.y != 0.f); m2 = (v.z != 0.f); m3 = (v.w != 0.f);
    }
    const unsigned long long b0 = __ballot(m0 != 0);
    const unsigned long long b1 = __ballot(m1 != 0);
    const unsigned long long b2 = __ballot(m2 != 0);
    const unsigned long long b3 = __ballot(m3 != 0);
    if (lane < 4) {
        const unsigned long long v = lane == 0 ? b0 : lane == 1 ? b1
                                   : lane == 2 ? b2 : b3;
        packed[row * 4 + lane] = v;
    }
}

// ---------------------------------------------------------------------------
// fp32 -> bf16 elementwise (float4 / us4 vectorized, grid-stride)
// ---------------------------------------------------------------------------
__global__ __launch_bounds__(256)
void f32_to_bf16_kernel(const float* __restrict__ in, unsigned short* __restrict__ out,
                        int n4)
{
    for (int i = blockIdx.x * 256 + threadIdx.x; i < n4; i += gridDim.x * 256) {
        const float4 v = ((const float4*)in)[i];
        us4 p;
        p[0] = f2bf(v.x); p[1] = f2bf(v.y); p[2] = f2bf(v.z); p[3] = f2bf(v.w);
        ((us4*)out)[i] = p;
    }
}

// ---------------------------------------------------------------------------
// Convert all 7 weight tensors to one contiguous bf16 region; additionally
// emit transposed copies of the three w1 matrices (for the combine gemm).
// ---------------------------------------------------------------------------
__global__ __launch_bounds__(256)
void convert_weights_kernel(const float* __restrict__ qw1, const float* __restrict__ kw1,
                            const float* __restrict__ vw1, const float* __restrict__ qw2,
                            const float* __restrict__ kw2, const float* __restrict__ vw2,
                            const float* __restrict__ pw,  unsigned short* __restrict__ out,
                            unsigned short* __restrict__ w1t)
{
    const int e = (blockIdx.x * 256 + threadIdx.x) * 4;   // element index
    const float* src; int off;
    if      (e < 65536)  { src = qw1; off = e; }
    else if (e < 131072) { src = kw1; off = e - 65536; }
    else if (e < 196608) { src = vw1; off = e - 131072; }
    else if (e < 262144) { src = qw2; off = e - 196608; }
    else if (e < 327680) { src = kw2; off = e - 262144; }
    else if (e < 393216) { src = vw2; off = e - 327680; }
    else                 { src = pw;  off = e - 393216; }
    const float4 v = *(const float4*)(src + off);
    us4 p;
    p[0] = f2bf(v.x); p[1] = f2bf(v.y); p[2] = f2bf(v.z); p[3] = f2bf(v.w);
    *(us4*)(out + e) = p;
    if (e < 196608) {   // w1 family: also store transposed (j,k) <- (k,j)
        const int mat = e >> 16, rem = e & 65535;
        const int k = rem >> 9, j = rem & 511;
#pragma unroll
        for (int t = 0; t < 4; ++t)
            w1t[mat * 65536 + (j + t) * 128 + k] = p[t];
    }
}

// ---------------------------------------------------------------------------
// bf16 MFMA GEMM: C(M,N) = A(M,K) @ B(N,K)^T. 128x128 tile, BK=64, 4 waves.
// 2-phase double-buffered LDS: issue next tile's global_load_lds, counted
// s_waitcnt vmcnt(8) (never 0 mid-loop), raw s_barrier; staging DMA overlaps
// MFMA of the current tile (T3-minimal recipe).
// OUT_MODE: 0 = f32 (+bias), 1 = bf16,
//           3 = kv split: col<512 -> k row-major; col>=512 -> v per-batch
//               transposed at Cp+1048576 elems.
// BSEL: B += (bm>>9)*65536 (per-512-row-block B select, combine gemm).
// ---------------------------------------------------------------------------
template<int OUT_MODE, int BSEL>
__global__ __launch_bounds__(256)
void gemm_bf16(const unsigned short* __restrict__ A,
               const unsigned short* __restrict__ B,
               const float* __restrict__ bias,
               void* __restrict__ Cp, int M, int N, int K)
{
    __shared__ unsigned short As[2][128 * 64];   // 2 x 16 KB
    __shared__ unsigned short Bs[2][128 * 64];   // 2 x 16 KB

    const int tid  = threadIdx.x;
    const int w    = tid >> 6;
    const int lane = tid & 63;
    const int c16  = lane & 15;
    const int g    = lane >> 4;
    const int wr   = w >> 1, wc = w & 1;      // 2x2 wave grid, 64x64 per wave
    const size_t bm = (size_t)blockIdx.y * 128;
    const size_t bn = (size_t)blockIdx.x * 128;
    if (BSEL) B += (bm >> 9) * 65536;

    f32x4 acc[4][4];
#pragma unroll
    for (int i = 0; i < 4; ++i)
#pragma unroll
        for (int j = 0; j < 4; ++j) acc[i][j] = (f32x4){0.f, 0.f, 0.f, 0.f};

    const int NT = K >> 6;

    // stage tile kt into buffer buf: 8 gload_lds per thread (4 A + 4 B)
    auto stage = [&](int buf, int kt) {
#pragma unroll
        for (int i = 0; i < 4; ++i) {
            const int o   = (((i * 4 + w) * 64) + lane) * 16;
            const int row = o >> 7;
            const int col = (o & 127) >> 1;
            gload_lds16(A + (bm + row) * K + kt + col, (char*)As[buf] + o);
        }
#pragma unroll
        for (int i = 0; i < 4; ++i) {
            const int o   = (((i * 4 + w) * 64) + lane) * 16;
            const int row = o >> 7;
            const int col = (o & 127) >> 1;
            gload_lds16(B + (bn + row) * K + kt + col, (char*)Bs[buf] + o);
        }
    };

    stage(0, 0);
    int cur = 0;
    for (int t = 0; t < NT; ++t) {
        if (t + 1 < NT) {
            stage(cur ^ 1, (t + 1) * 64);
            asm volatile("s_waitcnt vmcnt(8)" ::: "memory");  // cur's 8 landed; next 8 in flight
        } else {
            asm volatile("s_waitcnt vmcnt(0)" ::: "memory");
        }
        asm volatile("s_barrier" ::: "memory");
#pragma unroll
        for (int kk = 0; kk < 2; ++kk) {
            short8v a[4], bb[4];
#pragma unroll
            for (int mf = 0; mf < 4; ++mf)
                a[mf] = *(const short8v*)(&As[cur][(wr * 64 + mf * 16 + c16) * 64 + kk * 32 + g * 8]);
#pragma unroll
            for (int nf = 0; nf < 4; ++nf)
                bb[nf] = *(const short8v*)(&Bs[cur][(wc * 64 + nf * 16 + c16) * 64 + kk * 32 + g * 8]);
#pragma unroll
            for (int mf = 0; mf < 4; ++mf)
#pragma unroll
                for (int nf = 0; nf < 4; ++nf)
                    acc[mf][nf] = __builtin_amdgcn_mfma_f32_16x16x32_bf16(a[mf], bb[nf], acc[mf][nf], 0, 0, 0);
        }
        asm volatile("s_barrier" ::: "memory");   // readers done before buffer reuse
        cur ^= 1;
    }

    // epilogue: C/D layout col = lane&15, row = (lane>>4)*4 + reg
#pragma unroll
    for (int mf = 0; mf < 4; ++mf) {
#pragma unroll
        for (int nf = 0; nf < 4; ++nf) {
            const size_t col = bn + wc * 64 + nf * 16 + c16;
            const size_t r0  = bm + wr * 64 + mf * 16 + g * 4;
            if (OUT_MODE == 0) {
                float* C = (float*)Cp;
                const float bv = (bias != nullptr) ? bias[col] : 0.f;
#pragma unroll
                for (int r = 0; r < 4; ++r)
                    C[(r0 + r) * N + col] = acc[mf][nf][r] + bv;
            } else if (OUT_MODE == 1) {
                unsigned short* C = (unsigned short*)Cp;
#pragma unroll
                for (int r = 0; r < 4; ++r)
                    C[(r0 + r) * N + col] = f2bf(acc[mf][nf][r]);
            } else {
                if (col < 512) {
                    unsigned short* Ck = (unsigned short*)Cp;
#pragma unroll
                    for (int r = 0; r < 4; ++r)
                        Ck[(r0 + r) * 512 + col] = f2bf(acc[mf][nf][r]);
                } else {
                    unsigned short* Cv = (unsigned short*)Cp + 1048576;  // vt16
                    const size_t b  = r0 >> 8;
                    const size_t m0 = r0 & 255;
                    us4 p;
                    p[0] = f2bf(acc[mf][nf][0]); p[1] = f2bf(acc[mf][nf][1]);
                    p[2] = f2bf(acc[mf][nf][2]); p[3] = f2bf(acc[mf][nf][3]);
                    *(us4*)(Cv + (b * 512 + (col - 512)) * 256 + m0) = p;
                }
            }
        }
    }
}

// ---------------------------------------------------------------------------
// Fused depthwise 2x2/stride-2 conv + bias + LayerNorm over C -> bf16 out.
// ---------------------------------------------------------------------------
__global__ __launch_bounds__(512)
void conv_ln_kernel(const float* __restrict__ x, const float* __restrict__ srw,
                    const float* __restrict__ srb, const float* __restrict__ lng,
                    const float* __restrict__ lnb, unsigned short* __restrict__ xr)
{
    const int c  = threadIdx.x;
    const int bn = blockIdx.x;
    const int b  = bn >> 8;
    const int np = bn & 255;
    const int ho = np >> 4, wo = np & 15;
    const int n00 = (ho * 2) * 32 + wo * 2;

    const float* xb = x + ((size_t)b * NTOK) * DIMC + c;
    const float4 w = *(const float4*)(srw + c * 4);
    float y = srb[c]
            + xb[(size_t)(n00     ) * DIMC] * w.x
            + xb[(size_t)(n00 + 1 ) * DIMC] * w.y
            + xb[(size_t)(n00 + 32) * DIMC] * w.z
            + xb[(size_t)(n00 + 33) * DIMC] * w.w;

    float s = y, s2 = y * y;
#pragma unroll
    for (int off = 32; off > 0; off >>= 1) {
        s  += __shfl_down(s,  off);
        s2 += __shfl_down(s2, off);
    }
    __shared__ float red[16];
    __shared__ float stats[2];
    const int lane = c & 63, wid = c >> 6;
    if (lane == 0) { red[wid] = s; red[8 + wid] = s2; }
    __syncthreads();
    if (c == 0) {
        float ts = 0.f, ts2 = 0.f;
#pragma unroll
        for (int i = 0; i < 8; ++i) { ts += red[i]; ts2 += red[8 + i]; }
        const float mu  = ts * (1.f / 512.f);
        const float var = ts2 * (1.f / 512.f) - mu * mu;
        stats[0] = mu;
        stats[1] = rsqrtf(var + LN_EPS);
    }
    __syncthreads();
    const float mu = stats[0], rstd = stats[1];
    xr[((size_t)(b * MTOK + np)) * DIMC + c] = f2bf((y - mu) * rstd * lng[c] + lnb[c]);
}

// ---------------------------------------------------------------------------
// MFMA attention. Grid: 1024 = qt(16) x bh(64); blockIdx.x = qt*64 + bh so
// the 16 q-tiles of one (b,h) are 64 apart -> same XCD -> K/V L2-resident.
// Block: 256 = 4 waves; wave owns 16 query rows x all 256 keys.
// K h-slice (256x64 bf16 = 32 KB) is bulk-staged to LDS via global_load_lds
// with XOR swizzle (o ^= (row&7)<<4) applied on the GLOBAL source (m173);
// after QK^T a barrier retires K and the P tiles overwrite the same buffer.
// LDS stays 32 KB -> 4 blocks/CU with launch_bounds(256,4).
// ---------------------------------------------------------------------------
__global__ __launch_bounds__(256, 4)
void attn_mfma(const unsigned short* __restrict__ qb,
               const unsigned short* __restrict__ kb,
               const unsigned short* __restrict__ vt,
               const unsigned long long* __restrict__ pmask,
               unsigned short* __restrict__ ob)
{
    __shared__ unsigned short Ks[16384];   // 32 KB: K swizzled, then P tiles

    const int tid  = threadIdx.x;
    const int w    = tid >> 6;
    const int lane = tid & 63;
    const int g    = lane >> 4;
    const int c16  = lane & 15;
    const int bh   = blockIdx.x & 63;
    const int qt   = blockIdx.x >> 6;
    const int b    = bh >> 3;
    const int h    = bh & 7;
    const int q0   = qt * 64 + w * 16;

    // ---- stage K h-slice into LDS (swizzled via pre-swizzled global src) ----
    const unsigned short* kgb = kb + ((size_t)b * MTOK) * DIMC + h * HD;
#pragma unroll
    for (int t = 0; t < 8; ++t) {
        const int chunk = t * 256 + w * 64 + lane;        // [0,2048) 16B chunks
        const int o_dma = chunk * 16;                     // linear LDS dest
        const int row   = o_dma >> 7;
        const int o_log = o_dma ^ ((row & 7) << 4);       // involution
        const int slot  = (o_log >> 4) & 7;
        gload_lds16(kgb + (size_t)row * DIMC + slot * 8, (char*)Ks + o_dma);
    }

    // ---- independent global loads (hide under DMA wait) ----
    const size_t prow = (size_t)bh * NTOK + q0 + g * 4;
    unsigned mlo[4], mhi[4];
#pragma unroll
    for (int r = 0; r < 4; ++r) {
        const unsigned long long pm = pmask[(prow + r) * 4 + (c16 & 3)] >> (c16 >> 2);
        mlo[r] = (unsigned)pm;
        mhi[r] = (unsigned)(pm >> 32);
    }
    short8v qf[2];
#pragma unroll
    for (int ks = 0; ks < 2; ++ks)
        qf[ks] = *(const short8v*)(qb + ((size_t)(b * NTOK + q0 + c16)) * DIMC
                                      + h * HD + ks * 32 + g * 8);

    asm volatile("s_waitcnt vmcnt(0)" ::: "memory");
    asm volatile("s_barrier" ::: "memory");               // K tile ready

    // ---- S = Q @ K^T from LDS ----
    f32x4 s[16];
#pragma unroll
    for (int nf = 0; nf < 16; ++nf) s[nf] = (f32x4){0.f, 0.f, 0.f, 0.f};
#pragma unroll
    for (int nf = 0; nf < 16; ++nf) {
        const int kr = nf * 16 + c16;
        const int sw = (kr & 7) << 4;
#pragma unroll
        for (int ks = 0; ks < 2; ++ks) {
            const int o = (kr << 7) + ks * 64 + g * 16;
            const short8v kf = *(const short8v*)((const char*)Ks + (o ^ sw));
            s[nf] = __builtin_amdgcn_mfma_f32_16x16x32_bf16(qf[ks], kf, s[nf], 0, 0, 0);
        }
    }

    // ---- scale + mask (bits from packed words) ----
    const float scale = 0.125f;
#pragma unroll
    for (int nf = 0; nf < 16; ++nf) {
#pragma unroll
        for (int r = 0; r < 4; ++r) {
            const unsigned bit = ((nf < 8 ? (mlo[r] >> (nf * 4))
                                          : (mhi[r] >> ((nf - 8) * 4))) & 1u);
            s[nf][r] = bit ? -INFINITY : s[nf][r] * scale;
        }
    }

    // ---- row softmax (row in 16 lanes of group g, reg r) ----
    float mx[4] = {-1e30f, -1e30f, -1e30f, -1e30f};
#pragma unroll
    for (int nf = 0; nf < 16; ++nf)
#pragma unroll
        for (int r = 0; r < 4; ++r) mx[r] = fmaxf(mx[r], s[nf][r]);
#pragma unroll
    for (int off = 8; off >= 1; off >>= 1)
#pragma unroll
        for (int r = 0; r < 4; ++r) mx[r] = fmaxf(mx[r], __shfl_xor(mx[r], off, 64));

    float sm[4] = {0.f, 0.f, 0.f, 0.f};
#pragma unroll
    for (int nf = 0; nf < 16; ++nf)
#pragma unroll
        for (int r = 0; r < 4; ++r) {
            const float p = __expf(s[nf][r] - mx[r]);
            s[nf][r] = p;
            sm[r] += p;
        }
#pragma unroll
    for (int off = 8; off >= 1; off >>= 1)
#pragma unroll
        for (int r = 0; r < 4; ++r) sm[r] += __shfl_xor(sm[r], off, 64);
    float inv[4];
#pragma unroll
    for (int r = 0; r < 4; ++r) inv[r] = 1.0f / sm[r];

    asm volatile("s_barrier" ::: "memory");   // all waves done reading K

    // ---- P -> bf16 -> LDS (reuse K buffer; per-wave 8KB quadrant) ----
    unsigned short* pw = Ks + w * 4096;
#pragma unroll
    for (int nf = 0; nf < 16; ++nf) {
        const int key = nf * 16 + c16;
#pragma unroll
        for (int r = 0; r < 4; ++r) {
            const int row = g * 4 + r;
            pw[row * 256 + (key ^ ((row & 7) << 3))] = f2bf(s[nf][r] * inv[r]);
        }
    }

    // ---- O = P @ V : A from LDS, B from vt (contiguous keys, L2-hot) ----
    f32x4 o[4];
#pragma unroll
    for (int df = 0; df < 4; ++df) o[df] = (f32x4){0.f, 0.f, 0.f, 0.f};

    const int prw = c16;
    const unsigned short* pr = pw + prw * 256;
#pragma unroll
    for (int kf = 0; kf < 8; ++kf) {
        const int k0 = kf * 32 + g * 8;
        const short8v pa = *(const short8v*)(pr + (k0 ^ ((prw & 7) << 3)));
#pragma unroll
        for (int df = 0; df < 4; ++df) {
            const short8v vf = *(const short8v*)(vt + ((size_t)(b * DIMC + h * HD + df * 16 + c16)) * MTOK + k0);
            o[df] = __builtin_amdgcn_mfma_f32_16x16x32_bf16(pa, vf, o[df], 0, 0, 0);
        }
    }

#pragma unroll
    for (int df = 0; df < 4; ++df)
#pragma unroll
        for (int r = 0; r < 4; ++r)
            ob[((size_t)(b * NTOK + q0 + g * 4 + r)) * DIMC + h * HD + df * 16 + c16] =
                f2bf(o[df][r]);
}

// ---------------------------------------------------------------------------
extern "C" void kernel_launch(void* const* d_in, const int* in_sizes, int n_in,
                              void* d_out, int out_size, void* d_ws, size_t ws_size,
                              hipStream_t stream)
{
    const float* x      = (const float*)d_in[0];
    const void*  mask   = d_in[1];
    const float* q_w1   = (const float*)d_in[2];
    const float* q_w2   = (const float*)d_in[3];
    const float* k_w1   = (const float*)d_in[4];
    const float* k_w2   = (const float*)d_in[5];
    const float* v_w1   = (const float*)d_in[6];
    const float* v_w2   = (const float*)d_in[7];
    const float* sr_w   = (const float*)d_in[8];
    const float* sr_b   = (const float*)d_in[9];
    const float* ln_g   = (const float*)d_in[10];
    const float* ln_b   = (const float*)d_in[11];
    const float* proj_w = (const float*)d_in[12];
    const float* proj_b = (const float*)d_in[13];

    unsigned char* wsb = (unsigned char*)d_ws;
    unsigned short* xb16 = (unsigned short*)(wsb + 0);              // 8MB (dead after q gemm)
    unsigned short* ao16 = (unsigned short*)(wsb + 0);              // 8MB (reuses xb16)
    unsigned short* qb16 = (unsigned short*)(wsb + (8u  << 20));    // 8MB
    unsigned short* xrb  = (unsigned short*)(wsb + (16u << 20));    // 2MB
    unsigned short* w1t  = (unsigned short*)(wsb + (18u << 20));    // 384KB
    unsigned short* kb16 = (unsigned short*)(wsb + (19u << 20));    // 2MB
    unsigned short* vt16 = (unsigned short*)(wsb + (21u << 20));    // 2MB (= kb16 + 1048576 elems, mode-3 contract)
    unsigned short* wts  = (unsigned short*)(wsb + (23u << 20));    // 1.25MB
    unsigned short* wc16 = (unsigned short*)(wsb + (25u << 20));    // 1.5MB (combined 1536x512)
    unsigned long long* pmask = (unsigned long long*)(wsb + (27u << 20)); // 2MB
    int*            flag = (int*)(wsb + (29u << 20));

    const int QW2 = 196608, PW = 393216;

    detect_mask_kernel<<<1, 64, 0, stream>>>((const unsigned int*)mask, flag);
    pack_mask_kernel<<<16384, 256, 0, stream>>>(mask, flag, pmask);
    convert_weights_kernel<<<640, 256, 0, stream>>>(q_w1, k_w1, v_w1, q_w2, k_w2, v_w2,
                                                    proj_w, wts, w1t);
    f32_to_bf16_kernel<<<2048, 256, 0, stream>>>(x, xb16, 1048576);
    conv_ln_kernel<<<2048, 512, 0, stream>>>(x, sr_w, sr_b, ln_g, ln_b, xrb);

    // combined low-rank weights: WC(1536x512) = [q_w2;k_w2;v_w2] @ w1 (B select per 512 rows)
    gemm_bf16<1, 1><<<dim3(4, 12), 256, 0, stream>>>(wts + QW2, w1t, nullptr, wc16, 1536, 512, 128);

    // q = x @ Wq^T  (8192x512x512)
    gemm_bf16<1, 0><<<dim3(4, 64), 256, 0, stream>>>(xb16, wc16, nullptr, qb16, 8192, 512, 512);

    // [k | v] = xr @ [Wk;Wv]^T  (2048x1024x512), split epilogue k / v-transposed
    gemm_bf16<3, 0><<<dim3(8, 16), 256, 0, stream>>>(xrb, wc16 + 262144, nullptr, kb16, 2048, 1024, 512);

    // MFMA attention -> bf16 ao
    attn_mfma<<<1024, 256, 0, stream>>>(qb16, kb16, vt16, pmask, ao16);

    // output projection (+bias), bf16 MFMA, fp32 out
    gemm_bf16<0, 0><<<dim3(4, 64), 256, 0, stream>>>(ao16, wts + PW, proj_b, d_out, 8192, 512, 512);
}

// Round 7
// 207.581 us; speedup vs baseline: 3.5488x; 1.0627x over previous
//
#include <hip/hip_runtime.h>
#include <hip/hip_bf16.h>
#include <math.h>
#include <stdint.h>

#define DIMC   512
#define NHEAD  8
#define HD     64
#define NTOK   1024
#define MTOK   256
#define BSZ    8
#define LN_EPS 1e-5f

typedef __attribute__((ext_vector_type(8))) short  short8v;   // 8 bf16 (4 VGPR)
typedef __attribute__((ext_vector_type(4))) float  f32x4;     // MFMA C/D frag
typedef __attribute__((ext_vector_type(4))) unsigned short us4;

typedef const __attribute__((address_space(1))) unsigned int* gas1_t;
typedef __attribute__((address_space(3))) unsigned int*       las3_t;

__device__ __forceinline__ void gload_lds16(const void* g, void* l) {
    __builtin_amdgcn_global_load_lds((gas1_t)g, (las3_t)l, 16, 0, 0);
}

__device__ __forceinline__ unsigned short f2bf(float f) {
    union { float f; unsigned int u; } v; v.f = f;
    unsigned int u = v.u;
    return (unsigned short)((u + 0x7FFFu + ((u >> 16) & 1u)) >> 16);  // RNE, finite
}

// ---------------------------------------------------------------------------
// Bit-pack the (B,H,N,M) mask: per 256-key row -> 4 uint64 words.
// Self-probing dtype: each wave ballots the first 64 words (identical result
// in every wave): int32 0/1 words -> mtype 0; float 0/1.0f -> 2; else uint8.
// Wave handles one row: lane l loads keys 4l..4l+3; ballot j packs
// bit l = mask[4l+j]. Attn reads word (c16&3), bit (nf*4 + (c16>>2)).
// ---------------------------------------------------------------------------
__global__ __launch_bounds__(256)
void pack_mask_kernel(const void* __restrict__ maskp,
                      unsigned long long* __restrict__ packed)
{
    const int w = threadIdx.x >> 6, lane = threadIdx.x & 63;
    // dtype probe (wave-uniform, L2/L3-broadcast read)
    const unsigned int pw_ = ((const unsigned int*)maskp)[lane];
    const unsigned long long not01 = __ballot(pw_ > 1u);
    const unsigned long long notf  = __ballot(pw_ != 0u && pw_ != 0x3F800000u);
    const int mtype = (not01 == 0ull) ? 0 : ((notf == 0ull) ? 2 : 1);

    const long long row = (long long)blockIdx.x * 4 + w;   // 65536 rows
    int m0, m1, m2, m3;
    if (mtype == 0) {
        const int4 v = ((const int4*)maskp)[row * 64 + lane];
        m0 = v.x; m1 = v.y; m2 = v.z; m3 = v.w;
    } else if (mtype == 1) {
        const uchar4 v = ((const uchar4*)maskp)[row * 64 + lane];
        m0 = v.x; m1 = v.y; m2 = v.z; m3 = v.w;
    } else {
        const float4 v = ((const float4*)maskp)[row * 64 + lane];
        m0 = (v.x != 0.f); m1 = (v.y != 0.f); m2 = (v.z != 0.f); m3 = (v.w != 0.f);
    }
    const unsigned long long b0 = __ballot(m0 != 0);
    const unsigned long long b1 = __ballot(m1 != 0);
    const unsigned long long b2 = __ballot(m2 != 0);
    const unsigned long long b3 = __ballot(m3 != 0);
    if (lane < 4) {
        const unsigned long long v = lane == 0 ? b0 : lane == 1 ? b1
                                   : lane == 2 ? b2 : b3;
        packed[row * 4 + lane] = v;
    }
}

// ---------------------------------------------------------------------------
// Convert all 7 weight tensors to one contiguous bf16 region; additionally
// emit transposed copies of the three w1 matrices (for the combine gemm).
// ---------------------------------------------------------------------------
__global__ __launch_bounds__(256)
void convert_weights_kernel(const float* __restrict__ qw1, const float* __restrict__ kw1,
                            const float* __restrict__ vw1, const float* __restrict__ qw2,
                            const float* __restrict__ kw2, const float* __restrict__ vw2,
                            const float* __restrict__ pw,  unsigned short* __restrict__ out,
                            unsigned short* __restrict__ w1t)
{
    const int e = (blockIdx.x * 256 + threadIdx.x) * 4;   // element index
    const float* src; int off;
    if      (e < 65536)  { src = qw1; off = e; }
    else if (e < 131072) { src = kw1; off = e - 65536; }
    else if (e < 196608) { src = vw1; off = e - 131072; }
    else if (e < 262144) { src = qw2; off = e - 196608; }
    else if (e < 327680) { src = kw2; off = e - 262144; }
    else if (e < 393216) { src = vw2; off = e - 327680; }
    else                 { src = pw;  off = e - 393216; }
    const float4 v = *(const float4*)(src + off);
    us4 p;
    p[0] = f2bf(v.x); p[1] = f2bf(v.y); p[2] = f2bf(v.z); p[3] = f2bf(v.w);
    *(us4*)(out + e) = p;
    if (e < 196608) {   // w1 family: also store transposed (j,k) <- (k,j)
        const int mat = e >> 16, rem = e & 65535;
        const int k = rem >> 9, j = rem & 511;
#pragma unroll
        for (int t = 0; t < 4; ++t)
            w1t[mat * 65536 + (j + t) * 128 + k] = p[t];
    }
}

// ---------------------------------------------------------------------------
// Fused x prep: reads x once. Block = one output token (b,np), 512 threads =
// one channel each. Converts the 4 source tokens to bf16 (xb16) AND computes
// depthwise 2x2/s2 conv + bias + LayerNorm -> xrb (bf16).
// ---------------------------------------------------------------------------
__global__ __launch_bounds__(512)
void prep_x_kernel(const float* __restrict__ x, const float* __restrict__ srw,
                   const float* __restrict__ srb, const float* __restrict__ lng,
                   const float* __restrict__ lnb, unsigned short* __restrict__ xb16,
                   unsigned short* __restrict__ xr)
{
    const int c  = threadIdx.x;
    const int bn = blockIdx.x;
    const int b  = bn >> 8;
    const int np = bn & 255;
    const int ho = np >> 4, wo = np & 15;
    const int n00 = (ho * 2) * 32 + wo * 2;

    const size_t base = ((size_t)b * NTOK) * DIMC + c;
    const float x0 = x[base + (size_t)(n00     ) * DIMC];
    const float x1 = x[base + (size_t)(n00 + 1 ) * DIMC];
    const float x2 = x[base + (size_t)(n00 + 32) * DIMC];
    const float x3 = x[base + (size_t)(n00 + 33) * DIMC];

    xb16[base + (size_t)(n00     ) * DIMC] = f2bf(x0);
    xb16[base + (size_t)(n00 + 1 ) * DIMC] = f2bf(x1);
    xb16[base + (size_t)(n00 + 32) * DIMC] = f2bf(x2);
    xb16[base + (size_t)(n00 + 33) * DIMC] = f2bf(x3);

    const float4 w = *(const float4*)(srw + c * 4);
    float y = srb[c] + x0 * w.x + x1 * w.y + x2 * w.z + x3 * w.w;

    float s = y, s2 = y * y;
#pragma unroll
    for (int off = 32; off > 0; off >>= 1) {
        s  += __shfl_down(s,  off);
        s2 += __shfl_down(s2, off);
    }
    __shared__ float red[16];
    __shared__ float stats[2];
    const int lane = c & 63, wid = c >> 6;
    if (lane == 0) { red[wid] = s; red[8 + wid] = s2; }
    __syncthreads();
    if (c == 0) {
        float ts = 0.f, ts2 = 0.f;
#pragma unroll
        for (int i = 0; i < 8; ++i) { ts += red[i]; ts2 += red[8 + i]; }
        const float mu  = ts * (1.f / 512.f);
        const float var = ts2 * (1.f / 512.f) - mu * mu;
        stats[0] = mu;
        stats[1] = rsqrtf(var + LN_EPS);
    }
    __syncthreads();
    const float mu = stats[0], rstd = stats[1];
    xr[((size_t)(b * MTOK + np)) * DIMC + c] = f2bf((y - mu) * rstd * lng[c] + lnb[c]);
}

// ---------------------------------------------------------------------------
// bf16 MFMA GEMM: C(M,N) = A(M,K) @ B(N,K)^T. 64x128 tile, BK=64, 4 waves
// (2x2, each 32x64). 1-D grid with bijective XCD chunk swizzle (nwg%8==0):
// logical L = (b%8)*(nwg/8) + b/8 -> column-blocks sharing an A row-panel
// stay on one XCD. 2-phase dbuf, counted s_waitcnt vmcnt(6) (never 0 mid-loop).
// OUT_MODE: 0 = f32 (+bias), 1 = bf16,
//           3 = kv split: col<512 -> k row-major; col>=512 -> v per-batch
//               transposed at Cp+1048576 elems.
// BSEL: B += (bm>>9)*65536 (per-512-row-block B select, combine gemm).
// ---------------------------------------------------------------------------
template<int OUT_MODE, int BSEL>
__global__ __launch_bounds__(256)
void gemm_bf16(const unsigned short* __restrict__ A,
               const unsigned short* __restrict__ B,
               const float* __restrict__ bias,
               void* __restrict__ Cp, int M, int N, int K)
{
    __shared__ unsigned short As[2][64 * 64];    // 2 x 8 KB
    __shared__ unsigned short Bs[2][128 * 64];   // 2 x 16 KB

    const int tid  = threadIdx.x;
    const int w    = tid >> 6;
    const int lane = tid & 63;
    const int c16  = lane & 15;
    const int g    = lane >> 4;
    const int wr   = w >> 1, wc = w & 1;      // wave tile: rows wr*32, cols wc*64

    const int nwg = gridDim.x;
    const int L   = ((int)blockIdx.x & 7) * (nwg >> 3) + ((int)blockIdx.x >> 3);
    const int gx  = N >> 7;                   // blocks along N
    const size_t bm = (size_t)(L / gx) * 64;
    const size_t bn = (size_t)(L % gx) * 128;
    if (BSEL) B += (bm >> 9) * 65536;

    f32x4 acc[2][4];
#pragma unroll
    for (int i = 0; i < 2; ++i)
#pragma unroll
        for (int j = 0; j < 4; ++j) acc[i][j] = (f32x4){0.f, 0.f, 0.f, 0.f};

    const int NT = K >> 6;

    // stage tile kt into buffer buf: 6 gload_lds per thread (2 A + 4 B)
    auto stage = [&](int buf, int kt) {
#pragma unroll
        for (int i = 0; i < 2; ++i) {
            const int o   = (tid + i * 256) * 16;
            const int row = o >> 7;
            const int col = (o & 127) >> 1;
            gload_lds16(A + (bm + row) * K + kt + col, (char*)As[buf] + o);
        }
#pragma unroll
        for (int i = 0; i < 4; ++i) {
            const int o   = (tid + i * 256) * 16;
            const int row = o >> 7;
            const int col = (o & 127) >> 1;
            gload_lds16(B + (bn + row) * K + kt + col, (char*)Bs[buf] + o);
        }
    };

    stage(0, 0);
    int cur = 0;
    for (int t = 0; t < NT; ++t) {
        if (t + 1 < NT) {
            stage(cur ^ 1, (t + 1) * 64);
            asm volatile("s_waitcnt vmcnt(6)" ::: "memory");  // cur's 6 landed
        } else {
            asm volatile("s_waitcnt vmcnt(0)" ::: "memory");
        }
        asm volatile("s_barrier" ::: "memory");
#pragma unroll
        for (int kk = 0; kk < 2; ++kk) {
            short8v a[2], bb[4];
#pragma unroll
            for (int mf = 0; mf < 2; ++mf)
                a[mf] = *(const short8v*)(&As[cur][(wr * 32 + mf * 16 + c16) * 64 + kk * 32 + g * 8]);
#pragma unroll
            for (int nf = 0; nf < 4; ++nf)
                bb[nf] = *(const short8v*)(&Bs[cur][(wc * 64 + nf * 16 + c16) * 64 + kk * 32 + g * 8]);
#pragma unroll
            for (int mf = 0; mf < 2; ++mf)
#pragma unroll
                for (int nf = 0; nf < 4; ++nf)
                    acc[mf][nf] = __builtin_amdgcn_mfma_f32_16x16x32_bf16(a[mf], bb[nf], acc[mf][nf], 0, 0, 0);
        }
        asm volatile("s_barrier" ::: "memory");   // readers done before buffer reuse
        cur ^= 1;
    }

    // epilogue: C/D layout col = lane&15, row = (lane>>4)*4 + reg
#pragma unroll
    for (int mf = 0; mf < 2; ++mf) {
#pragma unroll
        for (int nf = 0; nf < 4; ++nf) {
            const size_t col = bn + wc * 64 + nf * 16 + c16;
            const size_t r0  = bm + wr * 32 + mf * 16 + g * 4;
            if (OUT_MODE == 0) {
                float* C = (float*)Cp;
                const float bv = (bias != nullptr) ? bias[col] : 0.f;
#pragma unroll
                for (int r = 0; r < 4; ++r)
                    C[(r0 + r) * N + col] = acc[mf][nf][r] + bv;
            } else if (OUT_MODE == 1) {
                unsigned short* C = (unsigned short*)Cp;
#pragma unroll
                for (int r = 0; r < 4; ++r)
                    C[(r0 + r) * N + col] = f2bf(acc[mf][nf][r]);
            } else {
                if (col < 512) {
                    unsigned short* Ck = (unsigned short*)Cp;
#pragma unroll
                    for (int r = 0; r < 4; ++r)
                        Ck[(r0 + r) * 512 + col] = f2bf(acc[mf][nf][r]);
                } else {
                    unsigned short* Cv = (unsigned short*)Cp + 1048576;  // vt16
                    const size_t b  = r0 >> 8;
                    const size_t m0 = r0 & 255;
                    us4 p;
                    p[0] = f2bf(acc[mf][nf][0]); p[1] = f2bf(acc[mf][nf][1]);
                    p[2] = f2bf(acc[mf][nf][2]); p[3] = f2bf(acc[mf][nf][3]);
                    *(us4*)(Cv + (b * 512 + (col - 512)) * 256 + m0) = p;
                }
            }
        }
    }
}

// ---------------------------------------------------------------------------
// MFMA attention. Grid: 1024 = qt(16) x bh(64); blockIdx.x = qt*64 + bh so
// the 16 q-tiles of one (b,h) are 64 apart -> same XCD -> K/V L2-resident.
// Block: 256 = 4 waves; wave owns 16 query rows x all 256 keys.
// K h-slice (256x64 bf16 = 32 KB) bulk-staged to LDS (pre-swizzled global
// source, o ^= (row&7)<<4); after QK^T a barrier retires K and P tiles
// overwrite the buffer. 32 KB LDS -> 4 blocks/CU via launch_bounds(256,4).
// ---------------------------------------------------------------------------
__global__ __launch_bounds__(256, 4)
void attn_mfma(const unsigned short* __restrict__ qb,
               const unsigned short* __restrict__ kb,
               const unsigned short* __restrict__ vt,
               const unsigned long long* __restrict__ pmask,
               unsigned short* __restrict__ ob)
{
    __shared__ unsigned short Ks[16384];   // 32 KB: K swizzled, then P tiles

    const int tid  = threadIdx.x;
    const int w    = tid >> 6;
    const int lane = tid & 63;
    const int g    = lane >> 4;
    const int c16  = lane & 15;
    const int bh   = blockIdx.x & 63;
    const int qt   = blockIdx.x >> 6;
    const int b    = bh >> 3;
    const int h    = bh & 7;
    const int q0   = qt * 64 + w * 16;

    // ---- stage K h-slice into LDS (swizzled via pre-swizzled global src) ----
    const unsigned short* kgb = kb + ((size_t)b * MTOK) * DIMC + h * HD;
#pragma unroll
    for (int t = 0; t < 8; ++t) {
        const int chunk = t * 256 + w * 64 + lane;        // [0,2048) 16B chunks
        const int o_dma = chunk * 16;                     // linear LDS dest
        const int row   = o_dma >> 7;
        const int o_log = o_dma ^ ((row & 7) << 4);       // involution
        const int slot  = (o_log >> 4) & 7;
        gload_lds16(kgb + (size_t)row * DIMC + slot * 8, (char*)Ks + o_dma);
    }

    // ---- independent global loads (hide under DMA wait) ----
    const size_t prow = (size_t)bh * NTOK + q0 + g * 4;
    unsigned mlo[4], mhi[4];
#pragma unroll
    for (int r = 0; r < 4; ++r) {
        const unsigned long long pm = pmask[(prow + r) * 4 + (c16 & 3)] >> (c16 >> 2);
        mlo[r] = (unsigned)pm;
        mhi[r] = (unsigned)(pm >> 32);
    }
    short8v qf[2];
#pragma unroll
    for (int ks = 0; ks < 2; ++ks)
        qf[ks] = *(const short8v*)(qb + ((size_t)(b * NTOK + q0 + c16)) * DIMC
                                      + h * HD + ks * 32 + g * 8);

    asm volatile("s_waitcnt vmcnt(0)" ::: "memory");
    asm volatile("s_barrier" ::: "memory");               // K tile ready

    // ---- S = Q @ K^T from LDS ----
    f32x4 s[16];
#pragma unroll
    for (int nf = 0; nf < 16; ++nf) s[nf] = (f32x4){0.f, 0.f, 0.f, 0.f};
    __builtin_amdgcn_s_setprio(1);
#pragma unroll
    for (int nf = 0; nf < 16; ++nf) {
        const int kr = nf * 16 + c16;
        const int sw = (kr & 7) << 4;
#pragma unroll
        for (int ks = 0; ks < 2; ++ks) {
            const int o = (kr << 7) + ks * 64 + g * 16;
            const short8v kf = *(const short8v*)((const char*)Ks + (o ^ sw));
            s[nf] = __builtin_amdgcn_mfma_f32_16x16x32_bf16(qf[ks], kf, s[nf], 0, 0, 0);
        }
    }
    __builtin_amdgcn_s_setprio(0);

    // ---- scale + mask (bits from packed words) ----
    const float scale = 0.125f;
#pragma unroll
    for (int nf = 0; nf < 16; ++nf) {
#pragma unroll
        for (int r = 0; r < 4; ++r) {
            const unsigned bit = ((nf < 8 ? (mlo[r] >> (nf * 4))
                                          : (mhi[r] >> ((nf - 8) * 4))) & 1u);
            s[nf][r] = bit ? -INFINITY : s[nf][r] * scale;
        }
    }

    // ---- row softmax (row in 16 lanes of group g, reg r) ----
    float mx[4] = {-1e30f, -1e30f, -1e30f, -1e30f};
#pragma unroll
    for (int nf = 0; nf < 16; ++nf)
#pragma unroll
        for (int r = 0; r < 4; ++r) mx[r] = fmaxf(mx[r], s[nf][r]);
#pragma unroll
    for (int off = 8; off >= 1; off >>= 1)
#pragma unroll
        for (int r = 0; r < 4; ++r) mx[r] = fmaxf(mx[r], __shfl_xor(mx[r], off, 64));

    float sm[4] = {0.f, 0.f, 0.f, 0.f};
#pragma unroll
    for (int nf = 0; nf < 16; ++nf)
#pragma unroll
        for (int r = 0; r < 4; ++r) {
            const float p = __expf(s[nf][r] - mx[r]);
            s[nf][r] = p;
            sm[r] += p;
        }
#pragma unroll
    for (int off = 8; off >= 1; off >>= 1)
#pragma unroll
        for (int r = 0; r < 4; ++r) sm[r] += __shfl_xor(sm[r], off, 64);
    float inv[4];
#pragma unroll
    for (int r = 0; r < 4; ++r) inv[r] = 1.0f / sm[r];

    asm volatile("s_barrier" ::: "memory");   // all waves done reading K

    // ---- P -> bf16 -> LDS (reuse K buffer; per-wave 8KB quadrant) ----
    unsigned short* pw = Ks + w * 4096;
#pragma unroll
    for (int nf = 0; nf < 16; ++nf) {
        const int key = nf * 16 + c16;
#pragma unroll
        for (int r = 0; r < 4; ++r) {
            const int row = g * 4 + r;
            pw[row * 256 + (key ^ ((row & 7) << 3))] = f2bf(s[nf][r] * inv[r]);
        }
    }

    // ---- O = P @ V : A from LDS, B from vt (contiguous keys, L2-hot) ----
    f32x4 o[4];
#pragma unroll
    for (int df = 0; df < 4; ++df) o[df] = (f32x4){0.f, 0.f, 0.f, 0.f};

    const int prw = c16;
    const unsigned short* pr = pw + prw * 256;
    __builtin_amdgcn_s_setprio(1);
#pragma unroll
    for (int kf = 0; kf < 8; ++kf) {
        const int k0 = kf * 32 + g * 8;
        const short8v pa = *(const short8v*)(pr + (k0 ^ ((prw & 7) << 3)));
#pragma unroll
        for (int df = 0; df < 4; ++df) {
            const short8v vf = *(const short8v*)(vt + ((size_t)(b * DIMC + h * HD + df * 16 + c16)) * MTOK + k0);
            o[df] = __builtin_amdgcn_mfma_f32_16x16x32_bf16(pa, vf, o[df], 0, 0, 0);
        }
    }
    __builtin_amdgcn_s_setprio(0);

#pragma unroll
    for (int df = 0; df < 4; ++df)
#pragma unroll
        for (int r = 0; r < 4; ++r)
            ob[((size_t)(b * NTOK + q0 + g * 4 + r)) * DIMC + h * HD + df * 16 + c16] =
                f2bf(o[df][r]);
}

// ---------------------------------------------------------------------------
extern "C" void kernel_launch(void* const* d_in, const int* in_sizes, int n_in,
                              void* d_out, int out_size, void* d_ws, size_t ws_size,
                              hipStream_t stream)
{
    const float* x      = (const float*)d_in[0];
    const void*  mask   = d_in[1];
    const float* q_w1   = (const float*)d_in[2];
    const float* q_w2   = (const float*)d_in[3];
    const float* k_w1   = (const float*)d_in[4];
    const float* k_w2   = (const float*)d_in[5];
    const float* v_w1   = (const float*)d_in[6];
    const float* v_w2   = (const float*)d_in[7];
    const float* sr_w   = (const float*)d_in[8];
    const float* sr_b   = (const float*)d_in[9];
    const float* ln_g   = (const float*)d_in[10];
    const float* ln_b   = (const float*)d_in[11];
    const float* proj_w = (const float*)d_in[12];
    const float* proj_b = (const float*)d_in[13];

    unsigned char* wsb = (unsigned char*)d_ws;
    unsigned short* xb16 = (unsigned short*)(wsb + 0);              // 8MB (dead after q gemm)
    unsigned short* ao16 = (unsigned short*)(wsb + 0);              // 8MB (reuses xb16)
    unsigned short* qb16 = (unsigned short*)(wsb + (8u  << 20));    // 8MB
    unsigned short* xrb  = (unsigned short*)(wsb + (16u << 20));    // 2MB
    unsigned short* w1t  = (unsigned short*)(wsb + (18u << 20));    // 384KB
    unsigned short* kb16 = (unsigned short*)(wsb + (19u << 20));    // 2MB
    unsigned short* vt16 = (unsigned short*)(wsb + (21u << 20));    // 2MB (= kb16 + 1048576 elems, mode-3 contract)
    unsigned short* wts  = (unsigned short*)(wsb + (23u << 20));    // 1.25MB
    unsigned short* wc16 = (unsigned short*)(wsb + (25u << 20));    // 1.5MB (combined 1536x512)
    unsigned long long* pmask = (unsigned long long*)(wsb + (27u << 20)); // 2MB

    const int QW2 = 196608, PW = 393216;

    pack_mask_kernel<<<16384, 256, 0, stream>>>(mask, pmask);
    convert_weights_kernel<<<640, 256, 0, stream>>>(q_w1, k_w1, v_w1, q_w2, k_w2, v_w2,
                                                    proj_w, wts, w1t);
    prep_x_kernel<<<2048, 512, 0, stream>>>(x, sr_w, sr_b, ln_g, ln_b, xb16, xrb);

    // combined low-rank weights: WC(1536x512) = [q_w2;k_w2;v_w2] @ w1 (B select per 512 rows)
    gemm_bf16<1, 1><<<96, 256, 0, stream>>>(wts + QW2, w1t, nullptr, wc16, 1536, 512, 128);

    // q = x @ Wq^T  (8192x512x512)
    gemm_bf16<1, 0><<<512, 256, 0, stream>>>(xb16, wc16, nullptr, qb16, 8192, 512, 512);

    // [k | v] = xr @ [Wk;Wv]^T  (2048x1024x512), split epilogue k / v-transposed
    gemm_bf16<3, 0><<<256, 256, 0, stream>>>(xrb, wc16 + 262144, nullptr, kb16, 2048, 1024, 512);

    // MFMA attention -> bf16 ao
    attn_mfma<<<1024, 256, 0, stream>>>(qb16, kb16, vt16, pmask, ao16);

    // output projection (+bias), bf16 MFMA, fp32 out
    gemm_bf16<0, 0><<<512, 256, 0, stream>>>(ao16, wts + PW, proj_b, d_out, 8192, 512, 512);
}

// Round 9
// 199.266 us; speedup vs baseline: 3.6969x; 1.0417x over previous
//
#include <hip/hip_runtime.h>
#include <hip/hip_bf16.h>
#include <math.h>
#include <stdint.h>

#define DIMC   512
#define NHEAD  8
#define HD     64
#define NTOK   1024
#define MTOK   256
#define BSZ    8
#define LN_EPS 1e-5f

typedef __attribute__((ext_vector_type(8))) short  short8v;   // 8 bf16 (4 VGPR)
typedef __attribute__((ext_vector_type(4))) float  f32x4;     // MFMA C/D frag
typedef __attribute__((ext_vector_type(4))) unsigned short us4;

typedef const __attribute__((address_space(1))) unsigned int* gas1_t;
typedef __attribute__((address_space(3))) unsigned int*       las3_t;

__device__ __forceinline__ void gload_lds16(const void* g, void* l) {
    __builtin_amdgcn_global_load_lds((gas1_t)g, (las3_t)l, 16, 0, 0);
}

__device__ __forceinline__ unsigned short f2bf(float f) {
    union { float f; unsigned int u; } v; v.f = f;
    unsigned int u = v.u;
    return (unsigned short)((u + 0x7FFFu + ((u >> 16) & 1u)) >> 16);  // RNE, finite
}

// ---------------------------------------------------------------------------
// prep_all: one dispatch, three roles by block range (all 256 threads).
//   [0, 16384)      : bit-pack mask (4 rows/block, self-probing dtype)
//   [16384, 17024)  : weight convert fp32->bf16 (+ w1 transposed copies)
//   [17024, 19072)  : x prep: x->bf16 AND depthwise conv+LN -> xrb
// ---------------------------------------------------------------------------
#define PM_BLKS 16384
#define CW_BLKS 640
#define PX_BLKS 2048

__global__ __launch_bounds__(256)
void prep_all_kernel(const void* __restrict__ maskp,
                     unsigned long long* __restrict__ packed,
                     const float* __restrict__ qw1, const float* __restrict__ kw1,
                     const float* __restrict__ vw1, const float* __restrict__ qw2,
                     const float* __restrict__ kw2, const float* __restrict__ vw2,
                     const float* __restrict__ pw,  unsigned short* __restrict__ wout,
                     unsigned short* __restrict__ w1t,
                     const float* __restrict__ x,   const float* __restrict__ srw,
                     const float* __restrict__ srb, const float* __restrict__ lng,
                     const float* __restrict__ lnb, unsigned short* __restrict__ xb16,
                     unsigned short* __restrict__ xr)
{
    const int blk = blockIdx.x;
    const int tid = threadIdx.x;

    if (blk < PM_BLKS) {
        // ---------------- mask bit-pack ----------------
        const int w = tid >> 6, lane = tid & 63;
        const unsigned int pw_ = ((const unsigned int*)maskp)[lane];
        const unsigned long long not01 = __ballot(pw_ > 1u);
        const unsigned long long notf  = __ballot(pw_ != 0u && pw_ != 0x3F800000u);
        const int mtype = (not01 == 0ull) ? 0 : ((notf == 0ull) ? 2 : 1);

        const long long row = (long long)blk * 4 + w;   // 65536 rows
        int m0, m1, m2, m3;
        if (mtype == 0) {
            const int4 v = ((const int4*)maskp)[row * 64 + lane];
            m0 = v.x; m1 = v.y; m2 = v.z; m3 = v.w;
        } else if (mtype == 1) {
            const uchar4 v = ((const uchar4*)maskp)[row * 64 + lane];
            m0 = v.x; m1 = v.y; m2 = v.z; m3 = v.w;
        } else {
            const float4 v = ((const float4*)maskp)[row * 64 + lane];
            m0 = (v.x != 0.f); m1 = (v.y != 0.f); m2 = (v.z != 0.f); m3 = (v.w != 0.f);
        }
        const unsigned long long b0 = __ballot(m0 != 0);
        const unsigned long long b1 = __ballot(m1 != 0);
        const unsigned long long b2 = __ballot(m2 != 0);
        const unsigned long long b3 = __ballot(m3 != 0);
        if (lane < 4) {
            const unsigned long long v = lane == 0 ? b0 : lane == 1 ? b1
                                       : lane == 2 ? b2 : b3;
            packed[row * 4 + lane] = v;
        }
        return;
    }

    if (blk < PM_BLKS + CW_BLKS) {
        // ---------------- weight convert ----------------
        const int e = ((blk - PM_BLKS) * 256 + tid) * 4;
        const float* src; int off;
        if      (e < 65536)  { src = qw1; off = e; }
        else if (e < 131072) { src = kw1; off = e - 65536; }
        else if (e < 196608) { src = vw1; off = e - 131072; }
        else if (e < 262144) { src = qw2; off = e - 196608; }
        else if (e < 327680) { src = kw2; off = e - 262144; }
        else if (e < 393216) { src = vw2; off = e - 327680; }
        else                 { src = pw;  off = e - 393216; }
        const float4 v = *(const float4*)(src + off);
        us4 p;
        p[0] = f2bf(v.x); p[1] = f2bf(v.y); p[2] = f2bf(v.z); p[3] = f2bf(v.w);
        *(us4*)(wout + e) = p;
        if (e < 196608) {   // w1 family: also store transposed (j,k) <- (k,j)
            const int mat = e >> 16, rem = e & 65535;
            const int k = rem >> 9, j = rem & 511;
#pragma unroll
            for (int t = 0; t < 4; ++t)
                w1t[mat * 65536 + (j + t) * 128 + k] = p[t];
        }
        return;
    }

    // ---------------- x prep (2 channels / thread) ----------------
    {
        const int bn = blk - (PM_BLKS + CW_BLKS);
        const int b  = bn >> 8;
        const int np = bn & 255;
        const int ho = np >> 4, wo = np & 15;
        const int n00 = (ho * 2) * 32 + wo * 2;

        float y[2];
#pragma unroll
        for (int half = 0; half < 2; ++half) {
            const int c = tid + half * 256;
            const size_t base = ((size_t)b * NTOK) * DIMC + c;
            const float x0 = x[base + (size_t)(n00     ) * DIMC];
            const float x1 = x[base + (size_t)(n00 + 1 ) * DIMC];
            const float x2 = x[base + (size_t)(n00 + 32) * DIMC];
            const float x3 = x[base + (size_t)(n00 + 33) * DIMC];
            xb16[base + (size_t)(n00     ) * DIMC] = f2bf(x0);
            xb16[base + (size_t)(n00 + 1 ) * DIMC] = f2bf(x1);
            xb16[base + (size_t)(n00 + 32) * DIMC] = f2bf(x2);
            xb16[base + (size_t)(n00 + 33) * DIMC] = f2bf(x3);
            const float4 w = *(const float4*)(srw + c * 4);
            y[half] = srb[c] + x0 * w.x + x1 * w.y + x2 * w.z + x3 * w.w;
        }

        float s  = y[0] + y[1];
        float s2 = y[0] * y[0] + y[1] * y[1];
#pragma unroll
        for (int off = 32; off > 0; off >>= 1) {
            s  += __shfl_down(s,  off);
            s2 += __shfl_down(s2, off);
        }
        __shared__ float red[8];
        __shared__ float stats[2];
        const int lane = tid & 63, wid = tid >> 6;
        if (lane == 0) { red[wid] = s; red[4 + wid] = s2; }
        __syncthreads();
        if (tid == 0) {
            float ts = 0.f, ts2 = 0.f;
#pragma unroll
            for (int i = 0; i < 4; ++i) { ts += red[i]; ts2 += red[4 + i]; }
            const float mu  = ts * (1.f / 512.f);
            const float var = ts2 * (1.f / 512.f) - mu * mu;
            stats[0] = mu;
            stats[1] = rsqrtf(var + LN_EPS);
        }
        __syncthreads();
        const float mu = stats[0], rstd = stats[1];
#pragma unroll
        for (int half = 0; half < 2; ++half) {
            const int c = tid + half * 256;
            xr[((size_t)(b * MTOK + np)) * DIMC + c] =
                f2bf((y[half] - mu) * rstd * lng[c] + lnb[c]);
        }
    }
}

// ---------------------------------------------------------------------------
// bf16 MFMA GEMM body: C(M,N) = A(M,K) @ B(N,K)^T. 64x128 tile, BK=64,
// 4 waves (2x2, each 32x64). Bijective XCD chunk swizzle (nwg%8==0).
// 2-phase dbuf, counted vmcnt(6).
// RACE FIX (r9): s_waitcnt lgkmcnt(0) BEFORE the buffer-reuse barrier —
// drains this wave's ds_reads into registers before any wave's next-tile
// global_load_lds DMA overwrites the buffer. Without it the compiler may
// sink the consuming MFMAs (register-only, unordered by "memory" clobbers)
// past the barrier, leaving reads pending across the reuse (rule #18 class).
// ---------------------------------------------------------------------------
template<int OUT_MODE, int BSEL>
__device__ __forceinline__
void gemm_body(const unsigned short* __restrict__ A,
               const unsigned short* __restrict__ B,
               const float* __restrict__ bias,
               void* __restrict__ Cp, int M, int N, int K, int lb, int nwg,
               unsigned short (*As)[64 * 64], unsigned short (*Bs)[128 * 64])
{
    const int tid  = threadIdx.x;
    const int w    = tid >> 6;
    const int lane = tid & 63;
    const int c16  = lane & 15;
    const int g    = lane >> 4;
    const int wr   = w >> 1, wc = w & 1;      // wave tile: rows wr*32, cols wc*64

    const int L   = (lb & 7) * (nwg >> 3) + (lb >> 3);
    const int gx  = N >> 7;                   // blocks along N
    const size_t bm = (size_t)(L / gx) * 64;
    const size_t bn = (size_t)(L % gx) * 128;
    if (BSEL) B += (bm >> 9) * 65536;

    f32x4 acc[2][4];
#pragma unroll
    for (int i = 0; i < 2; ++i)
#pragma unroll
        for (int j = 0; j < 4; ++j) acc[i][j] = (f32x4){0.f, 0.f, 0.f, 0.f};

    const int NT = K >> 6;

    auto stage = [&](int buf, int kt) {
#pragma unroll
        for (int i = 0; i < 2; ++i) {
            const int o   = (tid + i * 256) * 16;
            const int row = o >> 7;
            const int col = (o & 127) >> 1;
            gload_lds16(A + (bm + row) * K + kt + col, (char*)As[buf] + o);
        }
#pragma unroll
        for (int i = 0; i < 4; ++i) {
            const int o   = (tid + i * 256) * 16;
            const int row = o >> 7;
            const int col = (o & 127) >> 1;
            gload_lds16(B + (bn + row) * K + kt + col, (char*)Bs[buf] + o);
        }
    };

    stage(0, 0);
    int cur = 0;
    for (int t = 0; t < NT; ++t) {
        if (t + 1 < NT) {
            stage(cur ^ 1, (t + 1) * 64);
            asm volatile("s_waitcnt vmcnt(6)" ::: "memory");  // cur's 6 landed
        } else {
            asm volatile("s_waitcnt vmcnt(0)" ::: "memory");
        }
        asm volatile("s_barrier" ::: "memory");
#pragma unroll
        for (int kk = 0; kk < 2; ++kk) {
            short8v a[2], bb[4];
#pragma unroll
            for (int mf = 0; mf < 2; ++mf)
                a[mf] = *(const short8v*)(&As[cur][(wr * 32 + mf * 16 + c16) * 64 + kk * 32 + g * 8]);
#pragma unroll
            for (int nf = 0; nf < 4; ++nf)
                bb[nf] = *(const short8v*)(&Bs[cur][(wc * 64 + nf * 16 + c16) * 64 + kk * 32 + g * 8]);
#pragma unroll
            for (int mf = 0; mf < 2; ++mf)
#pragma unroll
                for (int nf = 0; nf < 4; ++nf)
                    acc[mf][nf] = __builtin_amdgcn_mfma_f32_16x16x32_bf16(a[mf], bb[nf], acc[mf][nf], 0, 0, 0);
        }
        asm volatile("s_waitcnt lgkmcnt(0)" ::: "memory");  // drain ds_reads (race fix)
        asm volatile("s_barrier" ::: "memory");             // then allow buffer reuse
        cur ^= 1;
    }

    // epilogue: C/D layout col = lane&15, row = (lane>>4)*4 + reg
#pragma unroll
    for (int mf = 0; mf < 2; ++mf) {
#pragma unroll
        for (int nf = 0; nf < 4; ++nf) {
            const size_t col = bn + wc * 64 + nf * 16 + c16;
            const size_t r0  = bm + wr * 32 + mf * 16 + g * 4;
            if (OUT_MODE == 0) {
                float* C = (float*)Cp;
                const float bv = (bias != nullptr) ? bias[col] : 0.f;
#pragma unroll
                for (int r = 0; r < 4; ++r)
                    C[(r0 + r) * N + col] = acc[mf][nf][r] + bv;
            } else if (OUT_MODE == 1) {
                unsigned short* C = (unsigned short*)Cp;
#pragma unroll
                for (int r = 0; r < 4; ++r)
                    C[(r0 + r) * N + col] = f2bf(acc[mf][nf][r]);
            } else {
                if (col < 512) {
                    unsigned short* Ck = (unsigned short*)Cp;
#pragma unroll
                    for (int r = 0; r < 4; ++r)
                        Ck[(r0 + r) * 512 + col] = f2bf(acc[mf][nf][r]);
                } else {
                    unsigned short* Cv = (unsigned short*)Cp + 1048576;  // vt16
                    const size_t b  = r0 >> 8;
                    const size_t m0 = r0 & 255;
                    us4 p;
                    p[0] = f2bf(acc[mf][nf][0]); p[1] = f2bf(acc[mf][nf][1]);
                    p[2] = f2bf(acc[mf][nf][2]); p[3] = f2bf(acc[mf][nf][3]);
                    *(us4*)(Cv + (b * 512 + (col - 512)) * 256 + m0) = p;
                }
            }
        }
    }
}

template<int OUT_MODE, int BSEL>
__global__ __launch_bounds__(256)
void gemm_bf16(const unsigned short* __restrict__ A,
               const unsigned short* __restrict__ B,
               const float* __restrict__ bias,
               void* __restrict__ Cp, int M, int N, int K)
{
    __shared__ unsigned short As[2][64 * 64];    // 2 x 8 KB
    __shared__ unsigned short Bs[2][128 * 64];   // 2 x 16 KB
    gemm_body<OUT_MODE, BSEL>(A, B, bias, Cp, M, N, K,
                              (int)blockIdx.x, (int)gridDim.x, As, Bs);
}

// ---------------------------------------------------------------------------
// Fused q + kv GEMM: blocks [0,512) do q = xb16 @ Wq^T (8192x512x512, bf16
// out); blocks [512,768) do [k|v] = xrb @ [Wk;Wv]^T (2048x1024x512, split
// epilogue). Independent outputs; kv blocks fill CUs alongside q blocks.
// ---------------------------------------------------------------------------
__global__ __launch_bounds__(256)
void gemm_qkv(const unsigned short* __restrict__ xb16,
              const unsigned short* __restrict__ xrb,
              const unsigned short* __restrict__ wc16,
              unsigned short* __restrict__ qb16,
              unsigned short* __restrict__ kb16)
{
    __shared__ unsigned short As[2][64 * 64];
    __shared__ unsigned short Bs[2][128 * 64];
    const int b = blockIdx.x;
    if (b < 512)
        gemm_body<1, 0>(xb16, wc16, nullptr, qb16, 8192, 512, 512, b, 512, As, Bs);
    else
        gemm_body<3, 0>(xrb, wc16 + 262144, nullptr, kb16, 2048, 1024, 512, b - 512, 256, As, Bs);
}

// ---------------------------------------------------------------------------
// MFMA attention. Grid: 1024 = qt(16) x bh(64); blockIdx.x = qt*64 + bh so
// the 16 q-tiles of one (b,h) are 64 apart -> same XCD -> K/V L2-resident.
// Block: 256 = 4 waves; wave owns 16 query rows x all 256 keys.
// K h-slice bulk-staged to LDS (pre-swizzled global source); after QK^T
// lgkmcnt(0)+barrier retires K and P tiles overwrite the buffer.
// ---------------------------------------------------------------------------
__global__ __launch_bounds__(256, 4)
void attn_mfma(const unsigned short* __restrict__ qb,
               const unsigned short* __restrict__ kb,
               const unsigned short* __restrict__ vt,
               const unsigned long long* __restrict__ pmask,
               unsigned short* __restrict__ ob)
{
    __shared__ unsigned short Ks[16384];   // 32 KB: K swizzled, then P tiles

    const int tid  = threadIdx.x;
    const int w    = tid >> 6;
    const int lane = tid & 63;
    const int g    = lane >> 4;
    const int c16  = lane & 15;
    const int bh   = blockIdx.x & 63;
    const int qt   = blockIdx.x >> 6;
    const int b    = bh >> 3;
    const int h    = bh & 7;
    const int q0   = qt * 64 + w * 16;

    // ---- stage K h-slice into LDS (swizzled via pre-swizzled global src) ----
    const unsigned short* kgb = kb + ((size_t)b * MTOK) * DIMC + h * HD;
#pragma unroll
    for (int t = 0; t < 8; ++t) {
        const int chunk = t * 256 + w * 64 + lane;        // [0,2048) 16B chunks
        const int o_dma = chunk * 16;                     // linear LDS dest
        const int row   = o_dma >> 7;
        const int o_log = o_dma ^ ((row & 7) << 4);       // involution
        const int slot  = (o_log >> 4) & 7;
        gload_lds16(kgb + (size_t)row * DIMC + slot * 8, (char*)Ks + o_dma);
    }

    // ---- independent global loads (hide under DMA wait) ----
    const size_t prow = (size_t)bh * NTOK + q0 + g * 4;
    unsigned mlo[4], mhi[4];
#pragma unroll
    for (int r = 0; r < 4; ++r) {
        const unsigned long long pm = pmask[(prow + r) * 4 + (c16 & 3)] >> (c16 >> 2);
        mlo[r] = (unsigned)pm;
        mhi[r] = (unsigned)(pm >> 32);
    }
    short8v qf[2];
#pragma unroll
    for (int ks = 0; ks < 2; ++ks)
        qf[ks] = *(const short8v*)(qb + ((size_t)(b * NTOK + q0 + c16)) * DIMC
                                      + h * HD + ks * 32 + g * 8);

    asm volatile("s_waitcnt vmcnt(0)" ::: "memory");
    asm volatile("s_barrier" ::: "memory");               // K tile ready

    // ---- S = Q @ K^T from LDS ----
    f32x4 s[16];
#pragma unroll
    for (int nf = 0; nf < 16; ++nf) s[nf] = (f32x4){0.f, 0.f, 0.f, 0.f};
    __builtin_amdgcn_s_setprio(1);
#pragma unroll
    for (int nf = 0; nf < 16; ++nf) {
        const int kr = nf * 16 + c16;
        const int sw = (kr & 7) << 4;
#pragma unroll
        for (int ks = 0; ks < 2; ++ks) {
            const int o = (kr << 7) + ks * 64 + g * 16;
            const short8v kf = *(const short8v*)((const char*)Ks + (o ^ sw));
            s[nf] = __builtin_amdgcn_mfma_f32_16x16x32_bf16(qf[ks], kf, s[nf], 0, 0, 0);
        }
    }
    __builtin_amdgcn_s_setprio(0);

    // ---- scale + mask (bits from packed words) ----
    const float scale = 0.125f;
#pragma unroll
    for (int nf = 0; nf < 16; ++nf) {
#pragma unroll
        for (int r = 0; r < 4; ++r) {
            const unsigned bit = ((nf < 8 ? (mlo[r] >> (nf * 4))
                                          : (mhi[r] >> ((nf - 8) * 4))) & 1u);
            s[nf][r] = bit ? -INFINITY : s[nf][r] * scale;
        }
    }

    // ---- row softmax (row in 16 lanes of group g, reg r) ----
    float mx[4] = {-1e30f, -1e30f, -1e30f, -1e30f};
#pragma unroll
    for (int nf = 0; nf < 16; ++nf)
#pragma unroll
        for (int r = 0; r < 4; ++r) mx[r] = fmaxf(mx[r], s[nf][r]);
#pragma unroll
    for (int off = 8; off >= 1; off >>= 1)
#pragma unroll
        for (int r = 0; r < 4; ++r) mx[r] = fmaxf(mx[r], __shfl_xor(mx[r], off, 64));

    float sm[4] = {0.f, 0.f, 0.f, 0.f};
#pragma unroll
    for (int nf = 0; nf < 16; ++nf)
#pragma unroll
        for (int r = 0; r < 4; ++r) {
            const float p = __expf(s[nf][r] - mx[r]);
            s[nf][r] = p;
            sm[r] += p;
        }
#pragma unroll
    for (int off = 8; off >= 1; off >>= 1)
#pragma unroll
        for (int r = 0; r < 4; ++r) sm[r] += __shfl_xor(sm[r], off, 64);
    float inv[4];
#pragma unroll
    for (int r = 0; r < 4; ++r) inv[r] = 1.0f / sm[r];

    asm volatile("s_waitcnt lgkmcnt(0)" ::: "memory");  // drain K reads (race fix)
    asm volatile("s_barrier" ::: "memory");             // all waves done reading K

    // ---- P -> bf16 -> LDS (reuse K buffer; per-wave 8KB quadrant) ----
    unsigned short* pw = Ks + w * 4096;
#pragma unroll
    for (int nf = 0; nf < 16; ++nf) {
        const int key = nf * 16 + c16;
#pragma unroll
        for (int r = 0; r < 4; ++r) {
            const int row = g * 4 + r;
            pw[row * 256 + (key ^ ((row & 7) << 3))] = f2bf(s[nf][r] * inv[r]);
        }
    }

    // ---- O = P @ V : A from LDS, B from vt (contiguous keys, L2-hot) ----
    f32x4 o[4];
#pragma unroll
    for (int df = 0; df < 4; ++df) o[df] = (f32x4){0.f, 0.f, 0.f, 0.f};

    const int prw = c16;
    const unsigned short* pr = pw + prw * 256;
    __builtin_amdgcn_s_setprio(1);
#pragma unroll
    for (int kf = 0; kf < 8; ++kf) {
        const int k0 = kf * 32 + g * 8;
        const short8v pa = *(const short8v*)(pr + (k0 ^ ((prw & 7) << 3)));
#pragma unroll
        for (int df = 0; df < 4; ++df) {
            const short8v vf = *(const short8v*)(vt + ((size_t)(b * DIMC + h * HD + df * 16 + c16)) * MTOK + k0);
            o[df] = __builtin_amdgcn_mfma_f32_16x16x32_bf16(pa, vf, o[df], 0, 0, 0);
        }
    }
    __builtin_amdgcn_s_setprio(0);

#pragma unroll
    for (int df = 0; df < 4; ++df)
#pragma unroll
        for (int r = 0; r < 4; ++r)
            ob[((size_t)(b * NTOK + q0 + g * 4 + r)) * DIMC + h * HD + df * 16 + c16] =
                f2bf(o[df][r]);
}

// ---------------------------------------------------------------------------
extern "C" void kernel_launch(void* const* d_in, const int* in_sizes, int n_in,
                              void* d_out, int out_size, void* d_ws, size_t ws_size,
                              hipStream_t stream)
{
    const float* x      = (const float*)d_in[0];
    const void*  mask   = d_in[1];
    const float* q_w1   = (const float*)d_in[2];
    const float* q_w2   = (const float*)d_in[3];
    const float* k_w1   = (const float*)d_in[4];
    const float* k_w2   = (const float*)d_in[5];
    const float* v_w1   = (const float*)d_in[6];
    const float* v_w2   = (const float*)d_in[7];
    const float* sr_w   = (const float*)d_in[8];
    const float* sr_b   = (const float*)d_in[9];
    const float* ln_g   = (const float*)d_in[10];
    const float* ln_b   = (const float*)d_in[11];
    const float* proj_w = (const float*)d_in[12];
    const float* proj_b = (const float*)d_in[13];

    unsigned char* wsb = (unsigned char*)d_ws;
    unsigned short* xb16 = (unsigned short*)(wsb + 0);              // 8MB (dead after q gemm)
    unsigned short* ao16 = (unsigned short*)(wsb + 0);              // 8MB (reuses xb16)
    unsigned short* qb16 = (unsigned short*)(wsb + (8u  << 20));    // 8MB
    unsigned short* xrb  = (unsigned short*)(wsb + (16u << 20));    // 2MB
    unsigned short* w1t  = (unsigned short*)(wsb + (18u << 20));    // 384KB
    unsigned short* kb16 = (unsigned short*)(wsb + (19u << 20));    // 2MB
    unsigned short* vt16 = (unsigned short*)(wsb + (21u << 20));    // 2MB (= kb16 + 1048576 elems, mode-3 contract)
    unsigned short* wts  = (unsigned short*)(wsb + (23u << 20));    // 1.25MB
    unsigned short* wc16 = (unsigned short*)(wsb + (25u << 20));    // 1.5MB (combined 1536x512)
    unsigned long long* pmask = (unsigned long long*)(wsb + (27u << 20)); // 2MB

    const int QW2 = 196608, PW = 393216;

    // one dispatch: mask pack + weight convert + x prep (independent roles)
    prep_all_kernel<<<PM_BLKS + CW_BLKS + PX_BLKS, 256, 0, stream>>>(
        mask, pmask, q_w1, k_w1, v_w1, q_w2, k_w2, v_w2, proj_w, wts, w1t,
        x, sr_w, sr_b, ln_g, ln_b, xb16, xrb);

    // combined low-rank weights: WC(1536x512) = [q_w2;k_w2;v_w2] @ w1 (B select per 512 rows)
    gemm_bf16<1, 1><<<96, 256, 0, stream>>>(wts + QW2, w1t, nullptr, wc16, 1536, 512, 128);

    // q = x @ Wq^T (8192x512x512) and [k|v] = xr @ [Wk;Wv]^T (2048x1024x512), fused
    gemm_qkv<<<768, 256, 0, stream>>>(xb16, xrb, wc16, qb16, kb16);

    // MFMA attention -> bf16 ao
    attn_mfma<<<1024, 256, 0, stream>>>(qb16, kb16, vt16, pmask, ao16);

    // output projection (+bias), bf16 MFMA, fp32 out
    gemm_bf16<0, 0><<<512, 256, 0, stream>>>(ao16, wts + PW, proj_b, d_out, 8192, 512, 512);
}